// Round 2
// baseline (2494.918 us; speedup 1.0000x reference)
//
#include <hip/hip_runtime.h>
#include <hip/hip_bf16.h>
#include <cstdint>

#define D  512
#define D2 1024
#define BB 128
#define SS 128
#define NN 196
#define TT 12

typedef unsigned short u16;

__device__ __forceinline__ float bf2f(u16 h){
  union { unsigned int u; float f; } v; v.u = ((unsigned int)h) << 16; return v.f;
}

// Generic scalar load: bf16 or fp32 per runtime flag (uniform). Loads sit
// behind a branch, never a select -> no speculative OOB of the 4B path.
__device__ __forceinline__ float LDX(const void* p, size_t i, int isbf){
  if (isbf) return bf2f(((const u16*)p)[i]);
  return ((const float*)p)[i];
}

// ---------------- detect input dtype from ctx bit patterns ----------------
__global__ __launch_bounds__(256) void k_detect(const u16* ctx, int* flag){
  __shared__ int cnt;
  if (threadIdx.x == 0) cnt = 0;
  __syncthreads();
  int bad = 0;
  for (int i = threadIdx.x; i < 8192; i += 256){
    int e = (ctx[i] >> 7) & 0xFF;
    if (e == 0xFF || (e != 0 && (e < 90 || e > 160))) bad++;
  }
  atomicAdd(&cnt, bad);
  __syncthreads();
  if (threadIdx.x == 0) *flag = (cnt > 100) ? 0 : 1;   // 1 = bf16, 0 = fp32
}

// ---------------- prep1: transposes / scaled copies of weights ----------------
__global__ __launch_bounds__(256) void k_prep1(const void* q, const void* Wcq, const void* Wca,
      const void* Wwc, const void* Wrm, const void* Wrc, const void* Wra,
      float* qT, float* W1f, float* Wwcf, float* WrmTf, float* W2f, const int* flag){
  const int isbf = *flag;
  __shared__ float lds[32][33];
  int bk = blockIdx.x, tid = threadIdx.x;
  int tx = tid & 31, ty = tid >> 5;
  if (bk >= 1152){
    int l = bk - 1152;
    if (isbf){
      const u16* w = (const u16*)Wrc; const u16* s = (const u16*)Wra;
      for (int idx = l*256 + tid; idx < 524288; idx += 64*256)
        W2f[idx] = bf2f(w[idx]) * bf2f(s[idx >> 10]);
    } else {
      const float* w = (const float*)Wrc; const float* s = (const float*)Wra;
      for (int idx = l*256 + tid; idx < 524288; idx += 64*256)
        W2f[idx] = w[idx] * s[idx >> 10];
    }
    return;
  }
  const void* in = nullptr; const void* scale = nullptr; float* out = nullptr;
  int ld = 0, R = 0, tR = 0, tC = 0;
  if (bk < 128)      { in = q;   ld = 1024; R = 128; out = qT;    tR = bk & 3;  tC = bk >> 2; }
  else if (bk < 384) { int l = bk - 128; in = Wcq; ld = 1024; R = 512; out = W1f;  scale = Wca; tR = l & 15; tC = l >> 4; }
  else if (bk < 896) { int l = bk - 384; in = Wwc; ld = 1024; R = 512; out = Wwcf; tR = l & 15; tC = l >> 4; }
  else               { int l = bk - 896; in = Wrm; ld = 512;  R = 512; out = WrmTf;tR = l & 15; tC = l >> 4; }
  int r0 = tR*32, c0 = tC*32;
  #pragma unroll
  for (int kk = 0; kk < 4; kk++){
    int r = r0 + ty + kk*8;
    float v = LDX(in, (size_t)r*ld + c0 + tx, isbf);
    if (scale) v *= LDX(scale, r, isbf);
    lds[tx][ty + kk*8] = v;
  }
  __syncthreads();
  #pragma unroll
  for (int kk = 0; kk < 4; kk++){
    int oc = ty + kk*8;
    out[(size_t)(c0 + oc)*R + r0 + tx] = lds[oc][tx];
  }
}

// ---------------- K_P: P[t,e,b] = sum_x qT[x,b]*Wp[t,e,x] + bp[t,e] ----------------
__global__ __launch_bounds__(256) void k_P(const float* qT, const void* Wp, const void* bp,
                                           float* P, const int* flag){
  const int isbf = *flag;
  int bk = blockIdx.x;                       // 768 = 12 * 64
  int t = bk >> 6, et = bk & 63;
  int tid = threadIdx.x;
  int b = tid & 127;
  int ih = __builtin_amdgcn_readfirstlane(tid >> 7);
  int e0 = et*8 + ih*4;
  float acc[4];
  #pragma unroll
  for (int kk = 0; kk < 4; kk++) acc[kk] = LDX(bp, t*D + e0 + kk, isbf);
  size_t wo = (size_t)(t*D + e0)*D2;
  if (isbf){
    const u16* wb = (const u16*)Wp + wo;
    for (int x = 0; x < D2; x += 4){
      float a0 = qT[(x+0)*BB + b], a1 = qT[(x+1)*BB + b];
      float a2 = qT[(x+2)*BB + b], a3 = qT[(x+3)*BB + b];
      #pragma unroll
      for (int kk = 0; kk < 4; kk++){
        ushort4 wv = *(const ushort4*)(wb + kk*D2 + x);
        acc[kk] += a0*bf2f(wv.x) + a1*bf2f(wv.y) + a2*bf2f(wv.z) + a3*bf2f(wv.w);
      }
    }
  } else {
    const float* wb = (const float*)Wp + wo;
    for (int x = 0; x < D2; x += 4){
      float a0 = qT[(x+0)*BB + b], a1 = qT[(x+1)*BB + b];
      float a2 = qT[(x+2)*BB + b], a3 = qT[(x+3)*BB + b];
      #pragma unroll
      for (int kk = 0; kk < 4; kk++){
        float4 wv = *(const float4*)(wb + kk*D2 + x);
        acc[kk] += a0*wv.x + a1*wv.y + a2*wv.z + a3*wv.w;
      }
    }
  }
  #pragma unroll
  for (int kk = 0; kk < 4; kk++) P[(size_t)(t*D + e0 + kk)*BB + b] = acc[kk];
}

// ---------------- K_pp2: pp2[t,j,b] = (sum_e P[t,e,b]*Wcq[j,D+e] + bcq[j]) * Wca[j] ----------------
__global__ __launch_bounds__(256) void k_pp2(const float* P, const void* Wcq, const void* bcq,
                                             const void* Wca, float* pp2, const int* flag){
  const int isbf = *flag;
  int bk = blockIdx.x;                       // 768
  int t = bk >> 6, jt = bk & 63;
  int tid = threadIdx.x;
  int b = tid & 127;
  int ih = __builtin_amdgcn_readfirstlane(tid >> 7);
  int j0 = jt*8 + ih*4;
  float acc[4];
  #pragma unroll
  for (int kk = 0; kk < 4; kk++) acc[kk] = LDX(bcq, j0 + kk, isbf);
  if (isbf){
    const u16* w = (const u16*)Wcq;
    for (int e = 0; e < D; e += 2){
      float a0 = P[(size_t)(t*D + e    )*BB + b];
      float a1 = P[(size_t)(t*D + e + 1)*BB + b];
      #pragma unroll
      for (int kk = 0; kk < 4; kk++){
        ushort2 wv = *(const ushort2*)(w + (size_t)(j0+kk)*D2 + D + e);
        acc[kk] += a0*bf2f(wv.x) + a1*bf2f(wv.y);
      }
    }
  } else {
    const float* w = (const float*)Wcq;
    for (int e = 0; e < D; e += 2){
      float a0 = P[(size_t)(t*D + e    )*BB + b];
      float a1 = P[(size_t)(t*D + e + 1)*BB + b];
      #pragma unroll
      for (int kk = 0; kk < 4; kk++){
        float2 wv = *(const float2*)(w + (size_t)(j0+kk)*D2 + D + e);
        acc[kk] += a0*wv.x + a1*wv.y;
      }
    }
  }
  #pragma unroll
  for (int kk = 0; kk < 4; kk++)
    pp2[(size_t)(t*D + j0 + kk)*BB + b] = acc[kk] * LDX(Wca, j0 + kk, isbf);
}

// ---------------- K_comp: WrmABf[e,i] = sum_d Wrm[i,d]*Wwc[d,e]; bmm[i] ----------------
__global__ __launch_bounds__(256) void k_comp(const float* WrmTf, const void* Wwc, const void* Wrm,
                                              const void* bwc, const void* brm,
                                              float* WrmABf, float* bmm, const int* flag){
  const int isbf = *flag;
  int bk = blockIdx.x, tid = threadIdx.x;
  if (bk < 512){
    int et = bk >> 2, ic = bk & 3;
    int i = ic*128 + (tid & 127);
    int ih = __builtin_amdgcn_readfirstlane(tid >> 7);
    int e0 = et*8 + ih*4;
    float acc[4] = {0.f, 0.f, 0.f, 0.f};
    if (isbf){
      const u16* w = (const u16*)Wwc;
      for (int d = 0; d < D; d++){
        float av = WrmTf[d*D + i];
        ushort4 wv = *(const ushort4*)(w + (size_t)d*D2 + e0);
        acc[0] += av*bf2f(wv.x); acc[1] += av*bf2f(wv.y);
        acc[2] += av*bf2f(wv.z); acc[3] += av*bf2f(wv.w);
      }
    } else {
      const float* w = (const float*)Wwc;
      for (int d = 0; d < D; d++){
        float av = WrmTf[d*D + i];
        float4 wv = *(const float4*)(w + (size_t)d*D2 + e0);
        acc[0] += av*wv.x; acc[1] += av*wv.y; acc[2] += av*wv.z; acc[3] += av*wv.w;
      }
    }
    #pragma unroll
    for (int kk = 0; kk < 4; kk++) WrmABf[(size_t)(e0+kk)*D + i] = acc[kk];
  } else {
    int i = (bk - 512)*256 + tid;
    float a = LDX(brm, i, isbf);
    for (int d = 0; d < D; d++) a += LDX(bwc, d, isbf) * LDX(Wrm, (size_t)i*D + d, isbf);
    bmm[i] = a;
  }
}

// ---------------- K_init: u0, mm0, m_{-1} ----------------
__global__ __launch_bounds__(256) void k_init(const void* ctrl0, const void* mem0, const void* Wcq,
                                              const void* Wca, const void* Wrm, const void* brm,
                                              const float* pp2, float* u0, float* mm0, float* act0,
                                              const int* flag){
  const int isbf = *flag;
  int bk = blockIdx.x, tid = threadIdx.x;
  int b = tid & 127;
  int ih = __builtin_amdgcn_readfirstlane(tid >> 7);
  if (bk < 64){
    int j0 = bk*8 + ih*4;
    #pragma unroll
    for (int kk = 0; kk < 4; kk++){
      int j = j0 + kk;
      float a = 0.f;
      for (int d = 0; d < D; d++) a += LDX(ctrl0, d, isbf) * LDX(Wcq, (size_t)j*D2 + d, isbf);
      u0[j*BB + b] = a * LDX(Wca, j, isbf) + pp2[j*BB + b];
    }
  } else if (bk < 128){
    int i0 = (bk - 64)*8 + ih*4;
    #pragma unroll
    for (int kk = 0; kk < 4; kk++){
      int i = i0 + kk;
      float a = LDX(brm, i, isbf);
      for (int d = 0; d < D; d++) a += LDX(mem0, d, isbf) * LDX(Wrm, (size_t)i*D + d, isbf);
      mm0[i*BB + b] = a;
    }
  } else {
    for (int x = (bk - 128)*256 + tid; x < D*BB; x += 8*256)
      act0[D*BB + x] = LDX(mem0, x >> 7, isbf);
  }
}

// ---------------- K_A1: ctx attention (per-batch block) + zero w ----------------
__global__ __launch_bounds__(256) void k_A1(const void* ctx, const float* ubuf, float* cbuf,
                                            float* wbuf, const int* flag){
  int bk = blockIdx.x, tid = threadIdx.x;
  if (bk >= BB){
    for (int x = (bk - BB)*256 + tid; x < D2*BB; x += 8*256) wbuf[x] = 0.f;
    return;
  }
  const int isbf = *flag;
  __shared__ float lg[SS];
  __shared__ float red[128];
  int b = bk;
  int lane = tid & 63, wv = tid >> 6;
  float ur[8];
  #pragma unroll
  for (int kk = 0; kk < 8; kk++) ur[kk] = ubuf[(lane*8 + kk)*BB + b];
  if (isbf){
    const u16* cb = (const u16*)ctx;
    for (int s = wv; s < SS; s += 4){
      const u16* crow = cb + ((size_t)(b*SS + s))*D + lane*8;
      ushort4 c0 = *(const ushort4*)crow;
      ushort4 c1 = *(const ushort4*)(crow + 4);
      float dot = ur[0]*bf2f(c0.x) + ur[1]*bf2f(c0.y) + ur[2]*bf2f(c0.z) + ur[3]*bf2f(c0.w)
                + ur[4]*bf2f(c1.x) + ur[5]*bf2f(c1.y) + ur[6]*bf2f(c1.z) + ur[7]*bf2f(c1.w);
      #pragma unroll
      for (int off = 32; off; off >>= 1) dot += __shfl_down(dot, off, 64);
      if (lane == 0) lg[s] = dot;
    }
  } else {
    const float* cb = (const float*)ctx;
    for (int s = wv; s < SS; s += 4){
      const float* crow = cb + ((size_t)(b*SS + s))*D + lane*8;
      float4 c0 = *(const float4*)crow;
      float4 c1 = *(const float4*)(crow + 4);
      float dot = ur[0]*c0.x + ur[1]*c0.y + ur[2]*c0.z + ur[3]*c0.w
                + ur[4]*c1.x + ur[5]*c1.y + ur[6]*c1.z + ur[7]*c1.w;
      #pragma unroll
      for (int off = 32; off; off >>= 1) dot += __shfl_down(dot, off, 64);
      if (lane == 0) lg[s] = dot;
    }
  }
  __syncthreads();
  if (tid < 128) red[tid] = lg[tid];
  __syncthreads();
  for (int off = 64; off; off >>= 1){ if (tid < off) red[tid] = fmaxf(red[tid], red[tid+off]); __syncthreads(); }
  float M = red[0];
  __syncthreads();
  if (tid < 128){ float e = __expf(lg[tid] - M); lg[tid] = e; red[tid] = e; }
  __syncthreads();
  for (int off = 64; off; off >>= 1){ if (tid < off) red[tid] += red[tid+off]; __syncthreads(); }
  float inv = 1.f / red[0];
  float accx = 0.f, accy = 0.f;
  if (isbf){
    const u16* cb = (const u16*)ctx + ((size_t)b*SS)*D + tid*2;
    for (int s = 0; s < SS; s++){
      float a = lg[s] * inv;
      ushort2 cv = *(const ushort2*)(cb + (size_t)s*D);
      accx += a*bf2f(cv.x); accy += a*bf2f(cv.y);
    }
  } else {
    const float* cb = (const float*)ctx + ((size_t)b*SS)*D + tid*2;
    for (int s = 0; s < SS; s++){
      float a = lg[s] * inv;
      float2 cv = *(const float2*)(cb + (size_t)s*D);
      accx += a*cv.x; accy += a*cv.y;
    }
  }
  cbuf[(tid*2 + 0)*BB + b] = accx;
  cbuf[(tid*2 + 1)*BB + b] = accy;
}

// ---------------- K_G2: w += c@W2f (atomic, K-split) + preload next-step accumulators ----------------
__global__ __launch_bounds__(256) void k_G2(const float* cbuf, const float* W2f, float* wbuf,
                                            const float* pp2_next, float* u_nxt,
                                            const float* bmm, float* mm_nxt,
                                            const void* bwc, float* act_nxt, int t, const int* flag){
  int bk = blockIdx.x, tid = threadIdx.x;
  if (bk < 256){
    int et = bk >> 1, kc = bk & 1;
    int b = tid & 127;
    int ih = __builtin_amdgcn_readfirstlane(tid >> 7);
    int e0 = et*8 + ih*4;
    float acc[4] = {0.f, 0.f, 0.f, 0.f};
    int j0 = kc*256;
    for (int j = j0; j < j0 + 256; j++){
      float av = cbuf[j*BB + b];
      float4 wv = *(const float4*)(W2f + (size_t)j*D2 + e0);
      acc[0] += av*wv.x; acc[1] += av*wv.y; acc[2] += av*wv.z; acc[3] += av*wv.w;
    }
    #pragma unroll
    for (int kk = 0; kk < 4; kk++) atomicAdd(&wbuf[(e0+kk)*BB + b], acc[kk]);
  } else if (bk < 272){
    if (t < TT-1)
      for (int x = (bk-256)*256 + tid; x < D*BB; x += 16*256) u_nxt[x] = pp2_next[x];
  } else if (bk < 288){
    if (t < TT-1)
      for (int x = (bk-272)*256 + tid; x < D*BB; x += 16*256) mm_nxt[x] = bmm[x >> 7];
  } else {
    const int isbf = *flag;
    if (isbf){
      const u16* w = (const u16*)bwc;
      for (int x = (bk-288)*256 + tid; x < D*BB; x += 16*256) act_nxt[D*BB + x] = bf2f(w[x >> 7]);
    } else {
      const float* w = (const float*)bwc;
      for (int x = (bk-288)*256 + tid; x < D*BB; x += 16*256) act_nxt[D*BB + x] = w[x >> 7];
    }
  }
}

// ---------------- K_A2: k attention (per-batch block) -> r into act_cur rows 0..511 ----------------
__global__ __launch_bounds__(256) void k_A2(const void* kmat, const float* wbuf,
                                            const float* mmbuf, float* act_cur, const int* flag){
  const int isbf = *flag;
  int b = blockIdx.x, tid = threadIdx.x;
  __shared__ float u2[D];
  __shared__ float lg[256];
  __shared__ float red[256];
  for (int d = tid; d < D; d += 256)
    u2[d] = wbuf[d*BB + b]*mmbuf[d*BB + b] + wbuf[(D + d)*BB + b];
  __syncthreads();
  float logit = -INFINITY;
  if (tid < NN){
    float acc = 0.f;
    if (isbf){
      const u16* kb = (const u16*)kmat + (size_t)b*D*NN + tid;
      for (int d = 0; d < D; d++) acc += u2[d]*bf2f(kb[(size_t)d*NN]);
    } else {
      const float* kb = (const float*)kmat + (size_t)b*D*NN + tid;
      for (int d = 0; d < D; d++) acc += u2[d]*kb[(size_t)d*NN];
    }
    logit = acc;
  }
  lg[tid] = logit;
  red[tid] = logit;
  __syncthreads();
  for (int off = 128; off; off >>= 1){ if (tid < off) red[tid] = fmaxf(red[tid], red[tid+off]); __syncthreads(); }
  float M = red[0];
  __syncthreads();
  float e = (tid < NN) ? __expf(lg[tid] - M) : 0.f;
  lg[tid] = e; red[tid] = e;
  __syncthreads();
  for (int off = 128; off; off >>= 1){ if (tid < off) red[tid] += red[tid+off]; __syncthreads(); }
  float inv = 1.f / red[0];
  int lane = tid & 63, wv = tid >> 6;
  if (isbf){
    for (int i = 0; i < 128; i++){
      int d = wv + i*4;
      const u16* krow = (const u16*)kmat + (size_t)b*D*NN + (size_t)d*NN;
      float p = lg[lane      ]*bf2f(krow[lane      ])
              + lg[lane +  64]*bf2f(krow[lane +  64])
              + lg[lane + 128]*bf2f(krow[lane + 128]);
      if (lane < NN - 192) p += lg[lane + 192]*bf2f(krow[lane + 192]);
      #pragma unroll
      for (int off = 32; off; off >>= 1) p += __shfl_down(p, off, 64);
      if (lane == 0) act_cur[d*BB + b] = p * inv;
    }
  } else {
    for (int i = 0; i < 128; i++){
      int d = wv + i*4;
      const float* krow = (const float*)kmat + (size_t)b*D*NN + (size_t)d*NN;
      float p = lg[lane      ]*krow[lane      ]
              + lg[lane +  64]*krow[lane +  64]
              + lg[lane + 128]*krow[lane + 128];
      if (lane < NN - 192) p += lg[lane + 192]*krow[lane + 192];
      #pragma unroll
      for (int off = 32; off; off >>= 1) p += __shfl_down(p, off, 64);
      if (lane == 0) act_cur[d*BB + b] = p * inv;
    }
  }
}

// ---------------- K_G3: m, mm_next, u_next (atomic K-split gemvs) ----------------
__global__ __launch_bounds__(256) void k_G3(const float* act_cur, const float* cbuf,
                                            const float* Wwcf, const float* WrmABf, const float* W1f,
                                            float* act_nxt, float* mm_nxt, float* u_nxt, int t){
  int bk = blockIdx.x, tid = threadIdx.x;
  int b = tid & 127;
  int ih = __builtin_amdgcn_readfirstlane(tid >> 7);
  if (bk < 128){
    int it = bk >> 2, kc = bk & 3;
    int i0 = it*16 + ih*8;
    float acc[8] = {0.f,0.f,0.f,0.f,0.f,0.f,0.f,0.f};
    int e0 = kc*256;
    for (int e = e0; e < e0 + 256; e++){
      float av = act_cur[e*BB + b];
      float4 w0 = *(const float4*)(Wwcf + (size_t)e*D + i0);
      float4 w1 = *(const float4*)(Wwcf + (size_t)e*D + i0 + 4);
      acc[0]+=av*w0.x; acc[1]+=av*w0.y; acc[2]+=av*w0.z; acc[3]+=av*w0.w;
      acc[4]+=av*w1.x; acc[5]+=av*w1.y; acc[6]+=av*w1.z; acc[7]+=av*w1.w;
    }
    #pragma unroll
    for (int kk = 0; kk < 8; kk++) atomicAdd(&act_nxt[(D + i0 + kk)*BB + b], acc[kk]);
  } else if (bk < 256){
    if (t == TT-1) return;
    int l = bk - 128;
    int it = l >> 2, kc = l & 3;
    int i0 = it*16 + ih*8;
    float acc[8] = {0.f,0.f,0.f,0.f,0.f,0.f,0.f,0.f};
    int e0 = kc*256;
    for (int e = e0; e < e0 + 256; e++){
      float av = act_cur[e*BB + b];
      float4 w0 = *(const float4*)(WrmABf + (size_t)e*D + i0);
      float4 w1 = *(const float4*)(WrmABf + (size_t)e*D + i0 + 4);
      acc[0]+=av*w0.x; acc[1]+=av*w0.y; acc[2]+=av*w0.z; acc[3]+=av*w0.w;
      acc[4]+=av*w1.x; acc[5]+=av*w1.y; acc[6]+=av*w1.z; acc[7]+=av*w1.w;
    }
    #pragma unroll
    for (int kk = 0; kk < 8; kk++) atomicAdd(&mm_nxt[(i0 + kk)*BB + b], acc[kk]);
  } else {
    if (t == TT-1) return;
    int l = bk - 256;
    int it = l >> 1, kc = l & 1;
    int j0 = it*16 + ih*8;
    float acc[8] = {0.f,0.f,0.f,0.f,0.f,0.f,0.f,0.f};
    int e0 = kc*256;
    for (int e = e0; e < e0 + 256; e++){
      float av = cbuf[e*BB + b];
      float4 w0 = *(const float4*)(W1f + (size_t)e*D + j0);
      float4 w1 = *(const float4*)(W1f + (size_t)e*D + j0 + 4);
      acc[0]+=av*w0.x; acc[1]+=av*w0.y; acc[2]+=av*w0.z; acc[3]+=av*w0.w;
      acc[4]+=av*w1.x; acc[5]+=av*w1.y; acc[6]+=av*w1.z; acc[7]+=av*w1.w;
    }
    #pragma unroll
    for (int kk = 0; kk < 8; kk++) atomicAdd(&u_nxt[(j0 + kk)*BB + b], acc[kk]);
  }
}

// ---------------- K_out: m[i,b] fp32 -> out[b,i] (bf16 or f32) ----------------
__global__ __launch_bounds__(256) void k_out(const float* act_fin, void* out, const int* flag){
  const int isbf = *flag;
  __shared__ float lds[32][33];
  int bk = blockIdx.x;                        // 64 = 16 i-tiles * 4 b-tiles
  int it = bk >> 2, bt = bk & 3;
  int tx = threadIdx.x & 31, ty = threadIdx.x >> 5;
  #pragma unroll
  for (int kk = 0; kk < 4; kk++){
    int i = it*32 + ty + kk*8;
    lds[tx][ty + kk*8] = act_fin[(D + i)*BB + bt*32 + tx];
  }
  __syncthreads();
  if (isbf){
    __hip_bfloat16* o = (__hip_bfloat16*)out;
    #pragma unroll
    for (int kk = 0; kk < 4; kk++){
      int bb = bt*32 + ty + kk*8;
      o[(size_t)bb*D + it*32 + tx] = __float2bfloat16(lds[ty + kk*8][tx]);
    }
  } else {
    float* o = (float*)out;
    #pragma unroll
    for (int kk = 0; kk < 4; kk++){
      int bb = bt*32 + ty + kk*8;
      o[(size_t)bb*D + it*32 + tx] = lds[ty + kk*8][tx];
    }
  }
}

extern "C" void kernel_launch(void* const* d_in, const int* in_sizes, int n_in,
                              void* d_out, int out_size, void* d_ws, size_t ws_size,
                              hipStream_t stream){
  const void* ctx  = d_in[0];
  const void* q    = d_in[1];
  const void* kmat = d_in[2];
  const void* mem0 = d_in[3];
  const void* ctrl0= d_in[4];
  const void* Wp   = d_in[5];
  const void* bp   = d_in[6];
  const void* Wcq  = d_in[7];
  const void* bcq  = d_in[8];
  const void* Wca  = d_in[9];
  const void* Wrm  = d_in[11];
  const void* brm  = d_in[12];
  const void* Wrc  = d_in[13];
  const void* Wra  = d_in[15];
  const void* Wwc  = d_in[17];
  const void* bwc  = d_in[18];

  float* W      = (float*)d_ws;
  float* qT     = W;
  float* P      = W + 131072;
  float* pp2    = W + 917504;
  float* W1f    = W + 1703936;
  float* W2f    = W + 1966080;
  float* Wwcf   = W + 2490368;
  float* WrmTf  = W + 3014656;
  float* WrmABf = W + 3276800;
  float* bmm    = W + 3801088;
  float* ubuf   = W + 3801600;   // 2 x 65536
  float* cbuf   = W + 3932672;
  float* wbuf   = W + 3998208;
  float* mmbuf  = W + 4129280;   // 2 x 65536
  float* actb   = W + 4260352;   // 2 x 131072
  int*   flag   = (int*)(W + 4522496);

  hipLaunchKernelGGL(k_detect, dim3(1), dim3(256), 0, stream, (const u16*)ctx, flag);
  hipLaunchKernelGGL(k_prep1, dim3(1216), dim3(256), 0, stream,
                     q, Wcq, Wca, Wwc, Wrm, Wrc, Wra, qT, W1f, Wwcf, WrmTf, W2f, flag);
  hipLaunchKernelGGL(k_P,    dim3(768), dim3(256), 0, stream, qT, Wp, bp, P, flag);
  hipLaunchKernelGGL(k_pp2,  dim3(768), dim3(256), 0, stream, P, Wcq, bcq, Wca, pp2, flag);
  hipLaunchKernelGGL(k_comp, dim3(514), dim3(256), 0, stream, WrmTf, Wwc, Wrm, bwc, brm, WrmABf, bmm, flag);
  hipLaunchKernelGGL(k_init, dim3(136), dim3(256), 0, stream,
                     ctrl0, mem0, Wcq, Wca, Wrm, brm, pp2, ubuf, mmbuf, actb, flag);

  for (int t = 0; t < TT; t++){
    int cur = t & 1, nxt = 1 - cur;
    hipLaunchKernelGGL(k_A1, dim3(136), dim3(256), 0, stream,
                       ctx, ubuf + cur*65536, cbuf, wbuf, flag);
    hipLaunchKernelGGL(k_G2, dim3(304), dim3(256), 0, stream,
                       cbuf, W2f, wbuf,
                       pp2 + ((t+1 < TT) ? (t+1)*65536 : 0), ubuf + nxt*65536,
                       bmm, mmbuf + nxt*65536,
                       bwc, actb + nxt*131072, t, flag);
    hipLaunchKernelGGL(k_A2, dim3(128), dim3(256), 0, stream,
                       kmat, wbuf, mmbuf + cur*65536, actb + cur*131072, flag);
    hipLaunchKernelGGL(k_G3, dim3(320), dim3(256), 0, stream,
                       actb + cur*131072, cbuf, Wwcf, WrmABf, W1f,
                       actb + nxt*131072, mmbuf + nxt*65536, ubuf + nxt*65536, t);
  }
  hipLaunchKernelGGL(k_out, dim3(64), dim3(256), 0, stream, actb, d_out, flag);
}

// Round 3
// 1948.978 us; speedup vs baseline: 1.2801x; 1.2801x over previous
//
#include <hip/hip_runtime.h>
#include <hip/hip_bf16.h>
#include <cstdint>

#define D  512
#define D2 1024
#define BB 128
#define SS 128
#define NN 196
#define TT 12

typedef unsigned short u16;

__device__ __forceinline__ float bf2f(u16 h){
  union { unsigned int u; float f; } v; v.u = ((unsigned int)h) << 16; return v.f;
}

__device__ __forceinline__ float LDX(const void* p, size_t i, int isbf){
  if (isbf) return bf2f(((const u16*)p)[i]);
  return ((const float*)p)[i];
}

__device__ __forceinline__ float4 LD4(const void* p, size_t i, int isbf){
  if (isbf){
    ushort4 w = *(const ushort4*)((const u16*)p + i);
    return make_float4(bf2f(w.x), bf2f(w.y), bf2f(w.z), bf2f(w.w));
  }
  return *(const float4*)((const float*)p + i);
}

// ---------------- detect input dtype from ctx bit patterns ----------------
__global__ __launch_bounds__(256) void k_detect(const u16* ctx, int* flag){
  __shared__ int cnt;
  if (threadIdx.x == 0) cnt = 0;
  __syncthreads();
  int bad = 0;
  for (int i = threadIdx.x; i < 8192; i += 256){
    int e = (ctx[i] >> 7) & 0xFF;
    if (e == 0xFF || (e != 0 && (e < 90 || e > 160))) bad++;
  }
  atomicAdd(&cnt, bad);
  __syncthreads();
  if (threadIdx.x == 0) *flag = (cnt > 100) ? 0 : 1;   // 1 = bf16, 0 = fp32
}

// ---------------- prep1: transposes / scaled copies of weights ----------------
__global__ __launch_bounds__(256) void k_prep1(const void* q, const void* Wcq, const void* Wca,
      const void* Wwc, const void* Wrm, const void* Wrc, const void* Wra,
      float* qT, float* W1f, float* Wwcf, float* WrmTf, float* W2f, const int* flag){
  const int isbf = *flag;
  __shared__ float lds[32][33];
  int bk = blockIdx.x, tid = threadIdx.x;
  int tx = tid & 31, ty = tid >> 5;
  if (bk >= 1152){
    int l = bk - 1152;
    if (isbf){
      const u16* w = (const u16*)Wrc; const u16* s = (const u16*)Wra;
      for (int idx = l*256 + tid; idx < 524288; idx += 64*256)
        W2f[idx] = bf2f(w[idx]) * bf2f(s[idx >> 10]);
    } else {
      const float* w = (const float*)Wrc; const float* s = (const float*)Wra;
      for (int idx = l*256 + tid; idx < 524288; idx += 64*256)
        W2f[idx] = w[idx] * s[idx >> 10];
    }
    return;
  }
  const void* in = nullptr; const void* scale = nullptr; float* out = nullptr;
  int ld = 0, R = 0, tR = 0, tC = 0;
  if (bk < 128)      { in = q;   ld = 1024; R = 128; out = qT;    tR = bk & 3;  tC = bk >> 2; }
  else if (bk < 384) { int l = bk - 128; in = Wcq; ld = 1024; R = 512; out = W1f;  scale = Wca; tR = l & 15; tC = l >> 4; }
  else if (bk < 896) { int l = bk - 384; in = Wwc; ld = 1024; R = 512; out = Wwcf; tR = l & 15; tC = l >> 4; }
  else               { int l = bk - 896; in = Wrm; ld = 512;  R = 512; out = WrmTf;tR = l & 15; tC = l >> 4; }
  int r0 = tR*32, c0 = tC*32;
  #pragma unroll
  for (int kk = 0; kk < 4; kk++){
    int r = r0 + ty + kk*8;
    float v = LDX(in, (size_t)r*ld + c0 + tx, isbf);
    if (scale) v *= LDX(scale, r, isbf);
    lds[tx][ty + kk*8] = v;
  }
  __syncthreads();
  #pragma unroll
  for (int kk = 0; kk < 4; kk++){
    int oc = ty + kk*8;
    out[(size_t)(c0 + oc)*R + r0 + tx] = lds[oc][tx];
  }
}

// ---------------- K_P: P[t,e,b] = sum_x qT[x,b]*Wp[t,e,x] + bp[t,e] ----------------
__global__ __launch_bounds__(256) void k_P(const float* qT, const void* Wp, const void* bp,
                                           float* P, const int* flag){
  const int isbf = *flag;
  int bk = blockIdx.x;                       // 768 = 12 * 64
  int t = bk >> 6, et = bk & 63;
  int tid = threadIdx.x;
  int b = tid & 127;
  int ih = __builtin_amdgcn_readfirstlane(tid >> 7);
  int e0 = et*8 + ih*4;
  float acc[4];
  #pragma unroll
  for (int kk = 0; kk < 4; kk++) acc[kk] = LDX(bp, t*D + e0 + kk, isbf);
  size_t wo = (size_t)(t*D + e0)*D2;
  if (isbf){
    const u16* wb = (const u16*)Wp + wo;
    for (int x = 0; x < D2; x += 4){
      float a0 = qT[(x+0)*BB + b], a1 = qT[(x+1)*BB + b];
      float a2 = qT[(x+2)*BB + b], a3 = qT[(x+3)*BB + b];
      #pragma unroll
      for (int kk = 0; kk < 4; kk++){
        ushort4 wv = *(const ushort4*)(wb + kk*D2 + x);
        acc[kk] += a0*bf2f(wv.x) + a1*bf2f(wv.y) + a2*bf2f(wv.z) + a3*bf2f(wv.w);
      }
    }
  } else {
    const float* wb = (const float*)Wp + wo;
    for (int x = 0; x < D2; x += 4){
      float a0 = qT[(x+0)*BB + b], a1 = qT[(x+1)*BB + b];
      float a2 = qT[(x+2)*BB + b], a3 = qT[(x+3)*BB + b];
      #pragma unroll
      for (int kk = 0; kk < 4; kk++){
        float4 wv = *(const float4*)(wb + kk*D2 + x);
        acc[kk] += a0*wv.x + a1*wv.y + a2*wv.z + a3*wv.w;
      }
    }
  }
  #pragma unroll
  for (int kk = 0; kk < 4; kk++) P[(size_t)(t*D + e0 + kk)*BB + b] = acc[kk];
}

// ---------------- K_pp2: pp2[t,j,b] = (sum_e P[t,e,b]*Wcq[j,D+e] + bcq[j]) * Wca[j] ----------------
__global__ __launch_bounds__(256) void k_pp2(const float* P, const void* Wcq, const void* bcq,
                                             const void* Wca, float* pp2, const int* flag){
  const int isbf = *flag;
  int bk = blockIdx.x;                       // 768
  int t = bk >> 6, jt = bk & 63;
  int tid = threadIdx.x;
  int b = tid & 127;
  int ih = __builtin_amdgcn_readfirstlane(tid >> 7);
  int j0 = jt*8 + ih*4;
  float acc[4];
  #pragma unroll
  for (int kk = 0; kk < 4; kk++) acc[kk] = LDX(bcq, j0 + kk, isbf);
  if (isbf){
    const u16* w = (const u16*)Wcq;
    for (int e = 0; e < D; e += 2){
      float a0 = P[(size_t)(t*D + e    )*BB + b];
      float a1 = P[(size_t)(t*D + e + 1)*BB + b];
      #pragma unroll
      for (int kk = 0; kk < 4; kk++){
        ushort2 wv = *(const ushort2*)(w + (size_t)(j0+kk)*D2 + D + e);
        acc[kk] += a0*bf2f(wv.x) + a1*bf2f(wv.y);
      }
    }
  } else {
    const float* w = (const float*)Wcq;
    for (int e = 0; e < D; e += 2){
      float a0 = P[(size_t)(t*D + e    )*BB + b];
      float a1 = P[(size_t)(t*D + e + 1)*BB + b];
      #pragma unroll
      for (int kk = 0; kk < 4; kk++){
        float2 wv = *(const float2*)(w + (size_t)(j0+kk)*D2 + D + e);
        acc[kk] += a0*wv.x + a1*wv.y;
      }
    }
  }
  #pragma unroll
  for (int kk = 0; kk < 4; kk++)
    pp2[(size_t)(t*D + j0 + kk)*BB + b] = acc[kk] * LDX(Wca, j0 + kk, isbf);
}

// ---------------- K_comp: WrmABf[e,i] = sum_d Wrm[i,d]*Wwc[d,e]; bmm[i] ----------------
__global__ __launch_bounds__(256) void k_comp(const float* WrmTf, const void* Wwc, const void* Wrm,
                                              const void* bwc, const void* brm,
                                              float* WrmABf, float* bmm, const int* flag){
  const int isbf = *flag;
  int bk = blockIdx.x, tid = threadIdx.x;
  if (bk < 512){
    int et = bk >> 2, ic = bk & 3;
    int i = ic*128 + (tid & 127);
    int ih = __builtin_amdgcn_readfirstlane(tid >> 7);
    int e0 = et*8 + ih*4;
    float acc[4] = {0.f, 0.f, 0.f, 0.f};
    if (isbf){
      const u16* w = (const u16*)Wwc;
      for (int d = 0; d < D; d++){
        float av = WrmTf[d*D + i];
        ushort4 wv = *(const ushort4*)(w + (size_t)d*D2 + e0);
        acc[0] += av*bf2f(wv.x); acc[1] += av*bf2f(wv.y);
        acc[2] += av*bf2f(wv.z); acc[3] += av*bf2f(wv.w);
      }
    } else {
      const float* w = (const float*)Wwc;
      for (int d = 0; d < D; d++){
        float av = WrmTf[d*D + i];
        float4 wv = *(const float4*)(w + (size_t)d*D2 + e0);
        acc[0] += av*wv.x; acc[1] += av*wv.y; acc[2] += av*wv.z; acc[3] += av*wv.w;
      }
    }
    #pragma unroll
    for (int kk = 0; kk < 4; kk++) WrmABf[(size_t)(e0+kk)*D + i] = acc[kk];
  } else {
    int i = (bk - 512)*256 + tid;
    float a = LDX(brm, i, isbf);
    for (int d = 0; d < D; d++) a += LDX(bwc, d, isbf) * LDX(Wrm, (size_t)i*D + d, isbf);
    bmm[i] = a;
  }
}

// ---------------- K_initA: b-independent base vectors via K-split reduction ----------------
// bk<16: ubase[j] = (sum_d ctrl0[d]*Wcq[j*D2+d]) * Wca[j],  j = bk*32..+31
// bk>=16: mmb[i]  = brm[i] + sum_d mem0[d]*Wrm[i*D+d],      i = (bk-16)*32..+31
__global__ __launch_bounds__(256) void k_initA(const void* ctrl0, const void* mem0,
                                               const void* Wcq, const void* Wca,
                                               const void* Wrm, const void* brm,
                                               float* ubase, float* mmb, const int* flag){
  const int isbf = *flag;
  int bk = blockIdx.x, tid = threadIdx.x;
  int lane = tid & 63, w = tid >> 6;          // 4 waves
  int grp = lane >> 3, k = lane & 7;          // 8 outputs/wave, 8 lanes/output
  int isU = (bk < 16);
  int o = (isU ? bk : bk - 16)*32 + w*8 + grp;
  const void* vec = isU ? ctrl0 : mem0;
  const void* mat = isU ? Wcq : Wrm;
  int ld = isU ? D2 : D;
  float acc = 0.f;
  #pragma unroll 4
  for (int it = 0; it < 16; it++){
    int d = it*32 + k*4;
    float4 v = LD4(vec, d, isbf);
    float4 m = LD4(mat, (size_t)o*ld + d, isbf);
    acc += v.x*m.x + v.y*m.y + v.z*m.z + v.w*m.w;
  }
  acc += __shfl_xor(acc, 1, 64);
  acc += __shfl_xor(acc, 2, 64);
  acc += __shfl_xor(acc, 4, 64);
  if (k == 0){
    if (isU) ubase[o] = acc * LDX(Wca, o, isbf);
    else     mmb[o]   = acc + LDX(brm, o, isbf);
  }
}

// ---------------- K_initB: broadcast u0, mm0, m_{-1} ----------------
__global__ __launch_bounds__(256) void k_initB(const float* ubase, const float* mmb,
                                               const void* mem0, const float* pp2,
                                               float* u0, float* mm0, float* act0, const int* flag){
  const int isbf = *flag;
  for (int idx = blockIdx.x*256 + threadIdx.x; idx < 3*D*BB; idx += 96*256){
    if (idx < D*BB)            u0[idx] = ubase[idx >> 7] + pp2[idx];
    else if (idx < 2*D*BB)   { int x = idx - D*BB;   mm0[x] = mmb[x >> 7]; }
    else                     { int x = idx - 2*D*BB; act0[D*BB + x] = LDX(mem0, x >> 7, isbf); }
  }
}

// ---------------- K_A1: ctx attention (per-batch block, 512 thr) + zero w ----------------
__global__ __launch_bounds__(512) void k_A1(const void* ctx, const float* ubuf, float* cbuf,
                                            float* wbuf, const int* flag){
  int bk = blockIdx.x, tid = threadIdx.x;
  if (bk >= BB){
    for (int x = (bk - BB)*512 + tid; x < D2*BB; x += 8*512) wbuf[x] = 0.f;
    return;
  }
  const int isbf = *flag;
  __shared__ float lg[SS];
  __shared__ float red[128];
  int b = bk;
  int lane = tid & 63, wv = tid >> 6;         // 8 waves
  float ur[8];
  #pragma unroll
  for (int kk = 0; kk < 8; kk++) ur[kk] = ubuf[(lane*8 + kk)*BB + b];
  if (isbf){
    const u16* cb = (const u16*)ctx;
    for (int s = wv; s < SS; s += 8){
      const u16* crow = cb + ((size_t)(b*SS + s))*D + lane*8;
      ushort4 c0 = *(const ushort4*)crow;
      ushort4 c1 = *(const ushort4*)(crow + 4);
      float dot = ur[0]*bf2f(c0.x) + ur[1]*bf2f(c0.y) + ur[2]*bf2f(c0.z) + ur[3]*bf2f(c0.w)
                + ur[4]*bf2f(c1.x) + ur[5]*bf2f(c1.y) + ur[6]*bf2f(c1.z) + ur[7]*bf2f(c1.w);
      #pragma unroll
      for (int off = 32; off; off >>= 1) dot += __shfl_down(dot, off, 64);
      if (lane == 0) lg[s] = dot;
    }
  } else {
    const float* cb = (const float*)ctx;
    for (int s = wv; s < SS; s += 8){
      const float* crow = cb + ((size_t)(b*SS + s))*D + lane*8;
      float4 c0 = *(const float4*)crow;
      float4 c1 = *(const float4*)(crow + 4);
      float dot = ur[0]*c0.x + ur[1]*c0.y + ur[2]*c0.z + ur[3]*c0.w
                + ur[4]*c1.x + ur[5]*c1.y + ur[6]*c1.z + ur[7]*c1.w;
      #pragma unroll
      for (int off = 32; off; off >>= 1) dot += __shfl_down(dot, off, 64);
      if (lane == 0) lg[s] = dot;
    }
  }
  __syncthreads();
  if (tid < 128) red[tid] = lg[tid];
  __syncthreads();
  for (int off = 64; off; off >>= 1){ if (tid < off) red[tid] = fmaxf(red[tid], red[tid+off]); __syncthreads(); }
  float M = red[0];
  __syncthreads();
  if (tid < 128){ float e = __expf(lg[tid] - M); lg[tid] = e; red[tid] = e; }
  __syncthreads();
  for (int off = 64; off; off >>= 1){ if (tid < off) red[tid] += red[tid+off]; __syncthreads(); }
  float inv = 1.f / red[0];
  // weighted sum: one d per thread, 4 independent acc chains
  int d = tid;
  float a0 = 0.f, a1 = 0.f, a2 = 0.f, a3 = 0.f;
  if (isbf){
    const u16* cb = (const u16*)ctx + ((size_t)b*SS)*D + d;
    #pragma unroll 2
    for (int s = 0; s < SS; s += 4){
      a0 += lg[s  ]*bf2f(cb[(size_t)(s  )*D]);
      a1 += lg[s+1]*bf2f(cb[(size_t)(s+1)*D]);
      a2 += lg[s+2]*bf2f(cb[(size_t)(s+2)*D]);
      a3 += lg[s+3]*bf2f(cb[(size_t)(s+3)*D]);
    }
  } else {
    const float* cb = (const float*)ctx + ((size_t)b*SS)*D + d;
    #pragma unroll 2
    for (int s = 0; s < SS; s += 4){
      a0 += lg[s  ]*cb[(size_t)(s  )*D];
      a1 += lg[s+1]*cb[(size_t)(s+1)*D];
      a2 += lg[s+2]*cb[(size_t)(s+2)*D];
      a3 += lg[s+3]*cb[(size_t)(s+3)*D];
    }
  }
  cbuf[d*BB + b] = ((a0 + a1) + (a2 + a3)) * inv;
}

// ---------------- K_G2: w += c@W2f (atomic, K-split) + preload next-step accumulators ----------------
__global__ __launch_bounds__(256) void k_G2(const float* cbuf, const float* W2f, float* wbuf,
                                            const float* pp2_next, float* u_nxt,
                                            const float* bmm, float* mm_nxt,
                                            const void* bwc, float* act_nxt, int t, const int* flag){
  int bk = blockIdx.x, tid = threadIdx.x;
  if (bk < 256){
    int et = bk >> 1, kc = bk & 1;
    int b = tid & 127;
    int ih = __builtin_amdgcn_readfirstlane(tid >> 7);
    int e0 = et*8 + ih*4;
    float acc[4] = {0.f, 0.f, 0.f, 0.f};
    int j0 = kc*256;
    for (int j = j0; j < j0 + 256; j++){
      float av = cbuf[j*BB + b];
      float4 wv = *(const float4*)(W2f + (size_t)j*D2 + e0);
      acc[0] += av*wv.x; acc[1] += av*wv.y; acc[2] += av*wv.z; acc[3] += av*wv.w;
    }
    #pragma unroll
    for (int kk = 0; kk < 4; kk++) atomicAdd(&wbuf[(e0+kk)*BB + b], acc[kk]);
  } else if (bk < 272){
    if (t < TT-1)
      for (int x = (bk-256)*256 + tid; x < D*BB; x += 16*256) u_nxt[x] = pp2_next[x];
  } else if (bk < 288){
    if (t < TT-1)
      for (int x = (bk-272)*256 + tid; x < D*BB; x += 16*256) mm_nxt[x] = bmm[x >> 7];
  } else {
    const int isbf = *flag;
    if (isbf){
      const u16* w = (const u16*)bwc;
      for (int x = (bk-288)*256 + tid; x < D*BB; x += 16*256) act_nxt[D*BB + x] = bf2f(w[x >> 7]);
    } else {
      const float* w = (const float*)bwc;
      for (int x = (bk-288)*256 + tid; x < D*BB; x += 16*256) act_nxt[D*BB + x] = w[x >> 7];
    }
  }
}

// ---------------- K_A2: k attention (per-batch block, 512 thr) -> r into act_cur ----------------
__global__ __launch_bounds__(512) void k_A2(const void* kmat, const float* wbuf,
                                            const float* mmbuf, float* act_cur, const int* flag){
  const int isbf = *flag;
  int b = blockIdx.x, tid = threadIdx.x;
  __shared__ float u2[D];
  __shared__ float lg[256];
  __shared__ float red[256];
  u2[tid] = wbuf[tid*BB + b]*mmbuf[tid*BB + b] + wbuf[(D + tid)*BB + b];
  __syncthreads();
  float logit = -INFINITY;
  if (tid < NN){
    float c0 = 0.f, c1 = 0.f, c2 = 0.f, c3 = 0.f;
    if (isbf){
      const u16* kb = (const u16*)kmat + (size_t)b*D*NN + tid;
      for (int d = 0; d < D; d += 4){
        c0 += u2[d  ]*bf2f(kb[(size_t)(d  )*NN]);
        c1 += u2[d+1]*bf2f(kb[(size_t)(d+1)*NN]);
        c2 += u2[d+2]*bf2f(kb[(size_t)(d+2)*NN]);
        c3 += u2[d+3]*bf2f(kb[(size_t)(d+3)*NN]);
      }
    } else {
      const float* kb = (const float*)kmat + (size_t)b*D*NN + tid;
      for (int d = 0; d < D; d += 4){
        c0 += u2[d  ]*kb[(size_t)(d  )*NN];
        c1 += u2[d+1]*kb[(size_t)(d+1)*NN];
        c2 += u2[d+2]*kb[(size_t)(d+2)*NN];
        c3 += u2[d+3]*kb[(size_t)(d+3)*NN];
      }
    }
    logit = (c0 + c1) + (c2 + c3);
  }
  if (tid < 256){ lg[tid] = logit; red[tid] = logit; }
  __syncthreads();
  for (int off = 128; off; off >>= 1){ if (tid < off) red[tid] = fmaxf(red[tid], red[tid+off]); __syncthreads(); }
  float M = red[0];
  __syncthreads();
  if (tid < 256){ float e = (tid < NN) ? __expf(lg[tid] - M) : 0.f; lg[tid] = e; red[tid] = e; }
  __syncthreads();
  for (int off = 128; off; off >>= 1){ if (tid < off) red[tid] += red[tid+off]; __syncthreads(); }
  float inv = 1.f / red[0];
  int lane = tid & 63, wv = tid >> 6;         // 8 waves
  if (isbf){
    for (int i = 0; i < 64; i++){
      int d = wv + i*8;
      const u16* krow = (const u16*)kmat + (size_t)b*D*NN + (size_t)d*NN;
      float p = lg[lane      ]*bf2f(krow[lane      ])
              + lg[lane +  64]*bf2f(krow[lane +  64])
              + lg[lane + 128]*bf2f(krow[lane + 128]);
      if (lane < NN - 192) p += lg[lane + 192]*bf2f(krow[lane + 192]);
      #pragma unroll
      for (int off = 32; off; off >>= 1) p += __shfl_down(p, off, 64);
      if (lane == 0) act_cur[d*BB + b] = p * inv;
    }
  } else {
    for (int i = 0; i < 64; i++){
      int d = wv + i*8;
      const float* krow = (const float*)kmat + (size_t)b*D*NN + (size_t)d*NN;
      float p = lg[lane      ]*krow[lane      ]
              + lg[lane +  64]*krow[lane +  64]
              + lg[lane + 128]*krow[lane + 128];
      if (lane < NN - 192) p += lg[lane + 192]*krow[lane + 192];
      #pragma unroll
      for (int off = 32; off; off >>= 1) p += __shfl_down(p, off, 64);
      if (lane == 0) act_cur[d*BB + b] = p * inv;
    }
  }
}

// ---------------- K_G3: m, mm_next, u_next (atomic K-split gemvs) ----------------
__global__ __launch_bounds__(256) void k_G3(const float* act_cur, const float* cbuf,
                                            const float* Wwcf, const float* WrmABf, const float* W1f,
                                            float* act_nxt, float* mm_nxt, float* u_nxt, int t){
  int bk = blockIdx.x, tid = threadIdx.x;
  int b = tid & 127;
  int ih = __builtin_amdgcn_readfirstlane(tid >> 7);
  if (bk < 128){
    int it = bk >> 2, kc = bk & 3;
    int i0 = it*16 + ih*8;
    float acc[8] = {0.f,0.f,0.f,0.f,0.f,0.f,0.f,0.f};
    int e0 = kc*256;
    for (int e = e0; e < e0 + 256; e++){
      float av = act_cur[e*BB + b];
      float4 w0 = *(const float4*)(Wwcf + (size_t)e*D + i0);
      float4 w1 = *(const float4*)(Wwcf + (size_t)e*D + i0 + 4);
      acc[0]+=av*w0.x; acc[1]+=av*w0.y; acc[2]+=av*w0.z; acc[3]+=av*w0.w;
      acc[4]+=av*w1.x; acc[5]+=av*w1.y; acc[6]+=av*w1.z; acc[7]+=av*w1.w;
    }
    #pragma unroll
    for (int kk = 0; kk < 8; kk++) atomicAdd(&act_nxt[(D + i0 + kk)*BB + b], acc[kk]);
  } else if (bk < 256){
    if (t == TT-1) return;
    int l = bk - 128;
    int it = l >> 2, kc = l & 3;
    int i0 = it*16 + ih*8;
    float acc[8] = {0.f,0.f,0.f,0.f,0.f,0.f,0.f,0.f};
    int e0 = kc*256;
    for (int e = e0; e < e0 + 256; e++){
      float av = act_cur[e*BB + b];
      float4 w0 = *(const float4*)(WrmABf + (size_t)e*D + i0);
      float4 w1 = *(const float4*)(WrmABf + (size_t)e*D + i0 + 4);
      acc[0]+=av*w0.x; acc[1]+=av*w0.y; acc[2]+=av*w0.z; acc[3]+=av*w0.w;
      acc[4]+=av*w1.x; acc[5]+=av*w1.y; acc[6]+=av*w1.z; acc[7]+=av*w1.w;
    }
    #pragma unroll
    for (int kk = 0; kk < 8; kk++) atomicAdd(&mm_nxt[(i0 + kk)*BB + b], acc[kk]);
  } else {
    if (t == TT-1) return;
    int l = bk - 256;
    int it = l >> 1, kc = l & 1;
    int j0 = it*16 + ih*8;
    float acc[8] = {0.f,0.f,0.f,0.f,0.f,0.f,0.f,0.f};
    int e0 = kc*256;
    for (int e = e0; e < e0 + 256; e++){
      float av = cbuf[e*BB + b];
      float4 w0 = *(const float4*)(W1f + (size_t)e*D + j0);
      float4 w1 = *(const float4*)(W1f + (size_t)e*D + j0 + 4);
      acc[0]+=av*w0.x; acc[1]+=av*w0.y; acc[2]+=av*w0.z; acc[3]+=av*w0.w;
      acc[4]+=av*w1.x; acc[5]+=av*w1.y; acc[6]+=av*w1.z; acc[7]+=av*w1.w;
    }
    #pragma unroll
    for (int kk = 0; kk < 8; kk++) atomicAdd(&u_nxt[(j0 + kk)*BB + b], acc[kk]);
  }
}

// ---------------- K_out: m[i,b] fp32 -> out[b,i] (bf16 or f32) ----------------
__global__ __launch_bounds__(256) void k_out(const float* act_fin, void* out, const int* flag){
  const int isbf = *flag;
  __shared__ float lds[32][33];
  int bk = blockIdx.x;                        // 64 = 16 i-tiles * 4 b-tiles
  int it = bk >> 2, bt = bk & 3;
  int tx = threadIdx.x & 31, ty = threadIdx.x >> 5;
  #pragma unroll
  for (int kk = 0; kk < 4; kk++){
    int i = it*32 + ty + kk*8;
    lds[tx][ty + kk*8] = act_fin[(D + i)*BB + bt*32 + tx];
  }
  __syncthreads();
  if (isbf){
    __hip_bfloat16* o = (__hip_bfloat16*)out;
    #pragma unroll
    for (int kk = 0; kk < 4; kk++){
      int bb = bt*32 + ty + kk*8;
      o[(size_t)bb*D + it*32 + tx] = __float2bfloat16(lds[ty + kk*8][tx]);
    }
  } else {
    float* o = (float*)out;
    #pragma unroll
    for (int kk = 0; kk < 4; kk++){
      int bb = bt*32 + ty + kk*8;
      o[(size_t)bb*D + it*32 + tx] = lds[ty + kk*8][tx];
    }
  }
}

extern "C" void kernel_launch(void* const* d_in, const int* in_sizes, int n_in,
                              void* d_out, int out_size, void* d_ws, size_t ws_size,
                              hipStream_t stream){
  const void* ctx  = d_in[0];
  const void* q    = d_in[1];
  const void* kmat = d_in[2];
  const void* mem0 = d_in[3];
  const void* ctrl0= d_in[4];
  const void* Wp   = d_in[5];
  const void* bp   = d_in[6];
  const void* Wcq  = d_in[7];
  const void* bcq  = d_in[8];
  const void* Wca  = d_in[9];
  const void* Wrm  = d_in[11];
  const void* brm  = d_in[12];
  const void* Wrc  = d_in[13];
  const void* Wra  = d_in[15];
  const void* Wwc  = d_in[17];
  const void* bwc  = d_in[18];

  float* W      = (float*)d_ws;
  float* qT     = W;
  float* P      = W + 131072;
  float* pp2    = W + 917504;
  float* W1f    = W + 1703936;
  float* W2f    = W + 1966080;
  float* Wwcf   = W + 2490368;
  float* WrmTf  = W + 3014656;
  float* WrmABf = W + 3276800;
  float* bmm    = W + 3801088;
  float* ubuf   = W + 3801600;   // 2 x 65536
  float* cbuf   = W + 3932672;
  float* wbuf   = W + 3998208;
  float* mmbuf  = W + 4129280;   // 2 x 65536
  float* actb   = W + 4260352;   // 2 x 131072
  int*   flag   = (int*)(W + 4522496);
  float* ubase  = W + 4522560;   // 512
  float* mmb    = W + 4523072;   // 512

  hipLaunchKernelGGL(k_detect, dim3(1), dim3(256), 0, stream, (const u16*)ctx, flag);
  hipLaunchKernelGGL(k_prep1, dim3(1216), dim3(256), 0, stream,
                     q, Wcq, Wca, Wwc, Wrm, Wrc, Wra, qT, W1f, Wwcf, WrmTf, W2f, flag);
  hipLaunchKernelGGL(k_P,    dim3(768), dim3(256), 0, stream, qT, Wp, bp, P, flag);
  hipLaunchKernelGGL(k_pp2,  dim3(768), dim3(256), 0, stream, P, Wcq, bcq, Wca, pp2, flag);
  hipLaunchKernelGGL(k_comp, dim3(514), dim3(256), 0, stream, WrmTf, Wwc, Wrm, bwc, brm, WrmABf, bmm, flag);
  hipLaunchKernelGGL(k_initA, dim3(32), dim3(256), 0, stream,
                     ctrl0, mem0, Wcq, Wca, Wrm, brm, ubase, mmb, flag);
  hipLaunchKernelGGL(k_initB, dim3(96), dim3(256), 0, stream,
                     ubase, mmb, mem0, pp2, ubuf, mmbuf, actb, flag);

  for (int t = 0; t < TT; t++){
    int cur = t & 1, nxt = 1 - cur;
    hipLaunchKernelGGL(k_A1, dim3(136), dim3(512), 0, stream,
                       ctx, ubuf + cur*65536, cbuf, wbuf, flag);
    hipLaunchKernelGGL(k_G2, dim3(304), dim3(256), 0, stream,
                       cbuf, W2f, wbuf,
                       pp2 + ((t+1 < TT) ? (t+1)*65536 : 0), ubuf + nxt*65536,
                       bmm, mmbuf + nxt*65536,
                       bwc, actb + nxt*131072, t, flag);
    hipLaunchKernelGGL(k_A2, dim3(128), dim3(512), 0, stream,
                       kmat, wbuf, mmbuf + cur*65536, actb + cur*131072, flag);
    hipLaunchKernelGGL(k_G3, dim3(320), dim3(256), 0, stream,
                       actb + cur*131072, cbuf, Wwcf, WrmABf, W1f,
                       actb + nxt*131072, mmbuf + nxt*65536, ubuf + nxt*65536, t);
  }
  hipLaunchKernelGGL(k_out, dim3(64), dim3(256), 0, stream, actb, d_out, flag);
}

// Round 4
// 1657.762 us; speedup vs baseline: 1.5050x; 1.1757x over previous
//
#include <hip/hip_runtime.h>
#include <hip/hip_bf16.h>
#include <cstdint>

#define D  512
#define D2 1024
#define BB 128
#define SS 128
#define NN 196
#define TT 12

typedef unsigned short u16;

__device__ __forceinline__ float bf2f(u16 h){
  union { unsigned int u; float f; } v; v.u = ((unsigned int)h) << 16; return v.f;
}

__device__ __forceinline__ float LDX(const void* p, size_t i, int isbf){
  if (isbf) return bf2f(((const u16*)p)[i]);
  return ((const float*)p)[i];
}

__device__ __forceinline__ float4 LD4(const void* p, size_t i, int isbf){
  if (isbf){
    ushort4 w = *(const ushort4*)((const u16*)p + i);
    return make_float4(bf2f(w.x), bf2f(w.y), bf2f(w.z), bf2f(w.w));
  }
  return *(const float4*)((const float*)p + i);
}

// ---------------- detect input dtype from ctx bit patterns ----------------
__global__ __launch_bounds__(256) void k_detect(const u16* ctx, int* flag){
  __shared__ int cnt;
  if (threadIdx.x == 0) cnt = 0;
  __syncthreads();
  int bad = 0;
  for (int i = threadIdx.x; i < 8192; i += 256){
    int e = (ctx[i] >> 7) & 0xFF;
    if (e == 0xFF || (e != 0 && (e < 90 || e > 160))) bad++;
  }
  atomicAdd(&cnt, bad);
  __syncthreads();
  if (threadIdx.x == 0) *flag = (cnt > 100) ? 0 : 1;   // 1 = bf16, 0 = fp32
}

// ---------------- prep1: transposes / scaled copies of weights ----------------
__global__ __launch_bounds__(256) void k_prep1(const void* q, const void* Wcq, const void* Wca,
      const void* Wwc, const void* Wrm, const void* Wrc, const void* Wra,
      float* qT, float* W1f, float* Wwcf, float* WrmTf, float* W2f, const int* flag){
  const int isbf = *flag;
  __shared__ float lds[32][33];
  int bk = blockIdx.x, tid = threadIdx.x;
  int tx = tid & 31, ty = tid >> 5;
  if (bk >= 1152){
    int l = bk - 1152;
    if (isbf){
      const u16* w = (const u16*)Wrc; const u16* s = (const u16*)Wra;
      for (int idx = l*256 + tid; idx < 524288; idx += 64*256)
        W2f[idx] = bf2f(w[idx]) * bf2f(s[idx >> 10]);
    } else {
      const float* w = (const float*)Wrc; const float* s = (const float*)Wra;
      for (int idx = l*256 + tid; idx < 524288; idx += 64*256)
        W2f[idx] = w[idx] * s[idx >> 10];
    }
    return;
  }
  const void* in = nullptr; const void* scale = nullptr; float* out = nullptr;
  int ld = 0, R = 0, tR = 0, tC = 0;
  if (bk < 128)      { in = q;   ld = 1024; R = 128; out = qT;    tR = bk & 3;  tC = bk >> 2; }
  else if (bk < 384) { int l = bk - 128; in = Wcq; ld = 1024; R = 512; out = W1f;  scale = Wca; tR = l & 15; tC = l >> 4; }
  else if (bk < 896) { int l = bk - 384; in = Wwc; ld = 1024; R = 512; out = Wwcf; tR = l & 15; tC = l >> 4; }
  else               { int l = bk - 896; in = Wrm; ld = 512;  R = 512; out = WrmTf;tR = l & 15; tC = l >> 4; }
  int r0 = tR*32, c0 = tC*32;
  #pragma unroll
  for (int kk = 0; kk < 4; kk++){
    int r = r0 + ty + kk*8;
    float v = LDX(in, (size_t)r*ld + c0 + tx, isbf);
    if (scale) v *= LDX(scale, r, isbf);
    lds[tx][ty + kk*8] = v;
  }
  __syncthreads();
  #pragma unroll
  for (int kk = 0; kk < 4; kk++){
    int oc = ty + kk*8;
    out[(size_t)(c0 + oc)*R + r0 + tx] = lds[oc][tx];
  }
}

// ---------------- K_P: P[t,e,b] = sum_x qT[x,b]*Wp[t,e,x] + bp[t,e] ----------------
__global__ __launch_bounds__(256) void k_P(const float* qT, const void* Wp, const void* bp,
                                           float* P, const int* flag){
  const int isbf = *flag;
  int bk = blockIdx.x;                       // 768 = 12 * 64
  int t = bk >> 6, et = bk & 63;
  int tid = threadIdx.x;
  int b = tid & 127;
  int ih = __builtin_amdgcn_readfirstlane(tid >> 7);
  int e0 = et*8 + ih*4;
  float acc[4];
  #pragma unroll
  for (int kk = 0; kk < 4; kk++) acc[kk] = LDX(bp, t*D + e0 + kk, isbf);
  size_t wo = (size_t)(t*D + e0)*D2;
  if (isbf){
    const u16* wb = (const u16*)Wp + wo;
    for (int x = 0; x < D2; x += 8){
      float a[8];
      #pragma unroll
      for (int u = 0; u < 8; u++) a[u] = qT[(x+u)*BB + b];
      #pragma unroll
      for (int kk = 0; kk < 4; kk++){
        ushort4 w0 = *(const ushort4*)(wb + kk*D2 + x);
        ushort4 w1 = *(const ushort4*)(wb + kk*D2 + x + 4);
        acc[kk] += a[0]*bf2f(w0.x) + a[1]*bf2f(w0.y) + a[2]*bf2f(w0.z) + a[3]*bf2f(w0.w)
                 + a[4]*bf2f(w1.x) + a[5]*bf2f(w1.y) + a[6]*bf2f(w1.z) + a[7]*bf2f(w1.w);
      }
    }
  } else {
    const float* wb = (const float*)Wp + wo;
    for (int x = 0; x < D2; x += 8){
      float a[8];
      #pragma unroll
      for (int u = 0; u < 8; u++) a[u] = qT[(x+u)*BB + b];
      #pragma unroll
      for (int kk = 0; kk < 4; kk++){
        float4 w0 = *(const float4*)(wb + kk*D2 + x);
        float4 w1 = *(const float4*)(wb + kk*D2 + x + 4);
        acc[kk] += a[0]*w0.x + a[1]*w0.y + a[2]*w0.z + a[3]*w0.w
                 + a[4]*w1.x + a[5]*w1.y + a[6]*w1.z + a[7]*w1.w;
      }
    }
  }
  #pragma unroll
  for (int kk = 0; kk < 4; kk++) P[(size_t)(t*D + e0 + kk)*BB + b] = acc[kk];
}

// ---------------- K_pp2: pp2[t,j,b] = (sum_e P[t,e,b]*Wcq[j,D+e] + bcq[j]) * Wca[j] ----------------
__global__ __launch_bounds__(256) void k_pp2(const float* P, const void* Wcq, const void* bcq,
                                             const void* Wca, float* pp2, const int* flag){
  const int isbf = *flag;
  int bk = blockIdx.x;                       // 768
  int t = bk >> 6, jt = bk & 63;
  int tid = threadIdx.x;
  int b = tid & 127;
  int ih = __builtin_amdgcn_readfirstlane(tid >> 7);
  int j0 = jt*8 + ih*4;
  float acc[4];
  #pragma unroll
  for (int kk = 0; kk < 4; kk++) acc[kk] = LDX(bcq, j0 + kk, isbf);
  if (isbf){
    const u16* w = (const u16*)Wcq;
    for (int e = 0; e < D; e += 8){
      float a[8];
      #pragma unroll
      for (int u = 0; u < 8; u++) a[u] = P[(size_t)(t*D + e + u)*BB + b];
      #pragma unroll
      for (int kk = 0; kk < 4; kk++){
        ushort4 w0 = *(const ushort4*)(w + (size_t)(j0+kk)*D2 + D + e);
        ushort4 w1 = *(const ushort4*)(w + (size_t)(j0+kk)*D2 + D + e + 4);
        acc[kk] += a[0]*bf2f(w0.x) + a[1]*bf2f(w0.y) + a[2]*bf2f(w0.z) + a[3]*bf2f(w0.w)
                 + a[4]*bf2f(w1.x) + a[5]*bf2f(w1.y) + a[6]*bf2f(w1.z) + a[7]*bf2f(w1.w);
      }
    }
  } else {
    const float* w = (const float*)Wcq;
    for (int e = 0; e < D; e += 8){
      float a[8];
      #pragma unroll
      for (int u = 0; u < 8; u++) a[u] = P[(size_t)(t*D + e + u)*BB + b];
      #pragma unroll
      for (int kk = 0; kk < 4; kk++){
        float4 w0 = *(const float4*)(w + (size_t)(j0+kk)*D2 + D + e);
        float4 w1 = *(const float4*)(w + (size_t)(j0+kk)*D2 + D + e + 4);
        acc[kk] += a[0]*w0.x + a[1]*w0.y + a[2]*w0.z + a[3]*w0.w
                 + a[4]*w1.x + a[5]*w1.y + a[6]*w1.z + a[7]*w1.w;
      }
    }
  }
  #pragma unroll
  for (int kk = 0; kk < 4; kk++)
    pp2[(size_t)(t*D + j0 + kk)*BB + b] = acc[kk] * LDX(Wca, j0 + kk, isbf);
}

// ---------------- K_comp: WrmABf[e,i] = sum_d Wrm[i,d]*Wwc[d,e]; bmm[i] ----------------
__global__ __launch_bounds__(256) void k_comp(const float* WrmTf, const void* Wwc, const void* Wrm,
                                              const void* bwc, const void* brm,
                                              float* WrmABf, float* bmm, const int* flag){
  const int isbf = *flag;
  int bk = blockIdx.x, tid = threadIdx.x;
  if (bk < 512){
    int et = bk >> 2, ic = bk & 3;
    int i = ic*128 + (tid & 127);
    int ih = __builtin_amdgcn_readfirstlane(tid >> 7);
    int e0 = et*8 + ih*4;
    float acc[4] = {0.f, 0.f, 0.f, 0.f};
    if (isbf){
      const u16* w = (const u16*)Wwc;
      for (int d = 0; d < D; d += 8){
        float av[8];
        #pragma unroll
        for (int u = 0; u < 8; u++) av[u] = WrmTf[(size_t)(d+u)*D + i];
        #pragma unroll
        for (int u = 0; u < 8; u++){
          ushort4 wv = *(const ushort4*)(w + (size_t)(d+u)*D2 + e0);
          acc[0] += av[u]*bf2f(wv.x); acc[1] += av[u]*bf2f(wv.y);
          acc[2] += av[u]*bf2f(wv.z); acc[3] += av[u]*bf2f(wv.w);
        }
      }
    } else {
      const float* w = (const float*)Wwc;
      for (int d = 0; d < D; d += 8){
        float av[8];
        #pragma unroll
        for (int u = 0; u < 8; u++) av[u] = WrmTf[(size_t)(d+u)*D + i];
        #pragma unroll
        for (int u = 0; u < 8; u++){
          float4 wv = *(const float4*)(w + (size_t)(d+u)*D2 + e0);
          acc[0] += av[u]*wv.x; acc[1] += av[u]*wv.y;
          acc[2] += av[u]*wv.z; acc[3] += av[u]*wv.w;
        }
      }
    }
    #pragma unroll
    for (int kk = 0; kk < 4; kk++) WrmABf[(size_t)(e0+kk)*D + i] = acc[kk];
  } else {
    int i = (bk - 512)*256 + tid;
    float a0 = LDX(brm, i, isbf), a1 = 0.f, a2 = 0.f, a3 = 0.f;
    for (int d = 0; d < D; d += 4){
      a0 += LDX(bwc, d  , isbf) * LDX(Wrm, (size_t)i*D + d  , isbf);
      a1 += LDX(bwc, d+1, isbf) * LDX(Wrm, (size_t)i*D + d+1, isbf);
      a2 += LDX(bwc, d+2, isbf) * LDX(Wrm, (size_t)i*D + d+2, isbf);
      a3 += LDX(bwc, d+3, isbf) * LDX(Wrm, (size_t)i*D + d+3, isbf);
    }
    bmm[i] = (a0 + a1) + (a2 + a3);
  }
}

// ---------------- K_initA: b-independent base vectors via K-split reduction ----------------
__global__ __launch_bounds__(256) void k_initA(const void* ctrl0, const void* mem0,
                                               const void* Wcq, const void* Wca,
                                               const void* Wrm, const void* brm,
                                               float* ubase, float* mmb, const int* flag){
  const int isbf = *flag;
  int bk = blockIdx.x, tid = threadIdx.x;
  int lane = tid & 63, w = tid >> 6;          // 4 waves
  int grp = lane >> 3, k = lane & 7;          // 8 outputs/wave, 8 lanes/output
  int isU = (bk < 16);
  int o = (isU ? bk : bk - 16)*32 + w*8 + grp;
  const void* vec = isU ? ctrl0 : mem0;
  const void* mat = isU ? Wcq : Wrm;
  int ld = isU ? D2 : D;
  float acc = 0.f;
  #pragma unroll 4
  for (int it = 0; it < 16; it++){
    int d = it*32 + k*4;
    float4 v = LD4(vec, d, isbf);
    float4 m = LD4(mat, (size_t)o*ld + d, isbf);
    acc += v.x*m.x + v.y*m.y + v.z*m.z + v.w*m.w;
  }
  acc += __shfl_xor(acc, 1, 64);
  acc += __shfl_xor(acc, 2, 64);
  acc += __shfl_xor(acc, 4, 64);
  if (k == 0){
    if (isU) ubase[o] = acc * LDX(Wca, o, isbf);
    else     mmb[o]   = acc + LDX(brm, o, isbf);
  }
}

// ---------------- K_initB: broadcast u0, mm0, m_{-1} ----------------
__global__ __launch_bounds__(256) void k_initB(const float* ubase, const float* mmb,
                                               const void* mem0, const float* pp2,
                                               float* u0, float* mm0, float* act0, const int* flag){
  const int isbf = *flag;
  for (int idx = blockIdx.x*256 + threadIdx.x; idx < 3*D*BB; idx += 96*256){
    if (idx < D*BB)            u0[idx] = ubase[idx >> 7] + pp2[idx];
    else if (idx < 2*D*BB)   { int x = idx - D*BB;   mm0[x] = mmb[x >> 7]; }
    else                     { int x = idx - 2*D*BB; act0[D*BB + x] = LDX(mem0, x >> 7, isbf); }
  }
}

// ---------------- K_A1: ctx attention (per-batch block, 512 thr) + zero w ----------------
__global__ __launch_bounds__(512) void k_A1(const void* ctx, const float* ubuf, float* cbuf,
                                            float* wbuf, const int* flag){
  int bk = blockIdx.x, tid = threadIdx.x;
  if (bk >= BB){
    for (int x = (bk - BB)*512 + tid; x < D2*BB; x += 8*512) wbuf[x] = 0.f;
    return;
  }
  const int isbf = *flag;
  __shared__ float lg[SS];
  __shared__ float red[128];
  int b = bk;
  int lane = tid & 63, wv = tid >> 6;         // 8 waves
  float ur[8];
  #pragma unroll
  for (int kk = 0; kk < 8; kk++) ur[kk] = ubuf[(lane*8 + kk)*BB + b];
  // logits: 2 interleaved s per wave-iteration
  for (int s = wv; s < SS; s += 16){
    int s2 = s + 8;
    float dotA, dotB;
    if (isbf){
      const u16* crowA = (const u16*)ctx + ((size_t)(b*SS + s ))*D + lane*8;
      const u16* crowB = (const u16*)ctx + ((size_t)(b*SS + s2))*D + lane*8;
      ushort4 a0 = *(const ushort4*)crowA, a1 = *(const ushort4*)(crowA + 4);
      ushort4 b0 = *(const ushort4*)crowB, b1 = *(const ushort4*)(crowB + 4);
      dotA = ur[0]*bf2f(a0.x) + ur[1]*bf2f(a0.y) + ur[2]*bf2f(a0.z) + ur[3]*bf2f(a0.w)
           + ur[4]*bf2f(a1.x) + ur[5]*bf2f(a1.y) + ur[6]*bf2f(a1.z) + ur[7]*bf2f(a1.w);
      dotB = ur[0]*bf2f(b0.x) + ur[1]*bf2f(b0.y) + ur[2]*bf2f(b0.z) + ur[3]*bf2f(b0.w)
           + ur[4]*bf2f(b1.x) + ur[5]*bf2f(b1.y) + ur[6]*bf2f(b1.z) + ur[7]*bf2f(b1.w);
    } else {
      const float* crowA = (const float*)ctx + ((size_t)(b*SS + s ))*D + lane*8;
      const float* crowB = (const float*)ctx + ((size_t)(b*SS + s2))*D + lane*8;
      float4 a0 = *(const float4*)crowA, a1 = *(const float4*)(crowA + 4);
      float4 b0 = *(const float4*)crowB, b1 = *(const float4*)(crowB + 4);
      dotA = ur[0]*a0.x + ur[1]*a0.y + ur[2]*a0.z + ur[3]*a0.w
           + ur[4]*a1.x + ur[5]*a1.y + ur[6]*a1.z + ur[7]*a1.w;
      dotB = ur[0]*b0.x + ur[1]*b0.y + ur[2]*b0.z + ur[3]*b0.w
           + ur[4]*b1.x + ur[5]*b1.y + ur[6]*b1.z + ur[7]*b1.w;
    }
    #pragma unroll
    for (int off = 32; off; off >>= 1){
      dotA += __shfl_down(dotA, off, 64);
      dotB += __shfl_down(dotB, off, 64);
    }
    if (lane == 0){ lg[s] = dotA; lg[s2] = dotB; }
  }
  __syncthreads();
  if (tid < 128) red[tid] = lg[tid];
  __syncthreads();
  for (int off = 64; off; off >>= 1){ if (tid < off) red[tid] = fmaxf(red[tid], red[tid+off]); __syncthreads(); }
  float M = red[0];
  __syncthreads();
  if (tid < 128){ float e = __expf(lg[tid] - M); lg[tid] = e; red[tid] = e; }
  __syncthreads();
  for (int off = 64; off; off >>= 1){ if (tid < off) red[tid] += red[tid+off]; __syncthreads(); }
  float inv = 1.f / red[0];
  // weighted sum: one d per thread, 8 independent acc chains
  int d = tid;
  float a[8];
  #pragma unroll
  for (int u = 0; u < 8; u++) a[u] = 0.f;
  if (isbf){
    const u16* cb = (const u16*)ctx + ((size_t)b*SS)*D + d;
    for (int s = 0; s < SS; s += 8){
      #pragma unroll
      for (int u = 0; u < 8; u++) a[u] += lg[s+u]*bf2f(cb[(size_t)(s+u)*D]);
    }
  } else {
    const float* cb = (const float*)ctx + ((size_t)b*SS)*D + d;
    for (int s = 0; s < SS; s += 8){
      #pragma unroll
      for (int u = 0; u < 8; u++) a[u] += lg[s+u]*cb[(size_t)(s+u)*D];
    }
  }
  cbuf[d*BB + b] = (((a[0]+a[1]) + (a[2]+a[3])) + ((a[4]+a[5]) + (a[6]+a[7]))) * inv;
}

// ---------------- K_G2: w += c@W2f (atomic, K-split) + preload next-step accumulators ----------------
__global__ __launch_bounds__(256) void k_G2(const float* cbuf, const float* W2f, float* wbuf,
                                            const float* pp2_next, float* u_nxt,
                                            const float* bmm, float* mm_nxt,
                                            const void* bwc, float* act_nxt, int t, const int* flag){
  int bk = blockIdx.x, tid = threadIdx.x;
  if (bk < 256){
    int et = bk >> 1, kc = bk & 1;
    int b = tid & 127;
    int ih = __builtin_amdgcn_readfirstlane(tid >> 7);
    int e0 = et*8 + ih*4;
    float acc[4] = {0.f, 0.f, 0.f, 0.f};
    int j0 = kc*256;
    for (int j = j0; j < j0 + 256; j += 4){
      float av[4];
      #pragma unroll
      for (int u = 0; u < 4; u++) av[u] = cbuf[(j+u)*BB + b];
      #pragma unroll
      for (int u = 0; u < 4; u++){
        float4 wv = *(const float4*)(W2f + (size_t)(j+u)*D2 + e0);
        acc[0] += av[u]*wv.x; acc[1] += av[u]*wv.y;
        acc[2] += av[u]*wv.z; acc[3] += av[u]*wv.w;
      }
    }
    #pragma unroll
    for (int kk = 0; kk < 4; kk++) atomicAdd(&wbuf[(e0+kk)*BB + b], acc[kk]);
  } else if (bk < 272){
    if (t < TT-1)
      for (int x = (bk-256)*256 + tid; x < D*BB; x += 16*256) u_nxt[x] = pp2_next[x];
  } else if (bk < 288){
    if (t < TT-1)
      for (int x = (bk-272)*256 + tid; x < D*BB; x += 16*256) mm_nxt[x] = bmm[x >> 7];
  } else {
    const int isbf = *flag;
    if (isbf){
      const u16* w = (const u16*)bwc;
      for (int x = (bk-288)*256 + tid; x < D*BB; x += 16*256) act_nxt[D*BB + x] = bf2f(w[x >> 7]);
    } else {
      const float* w = (const float*)bwc;
      for (int x = (bk-288)*256 + tid; x < D*BB; x += 16*256) act_nxt[D*BB + x] = w[x >> 7];
    }
  }
}

// ---------------- K_A2: k attention (per-batch block, 512 thr) -> r into act_cur ----------------
__global__ __launch_bounds__(512) void k_A2(const void* kmat, const float* wbuf,
                                            const float* mmbuf, float* act_cur, const int* flag){
  const int isbf = *flag;
  int b = blockIdx.x, tid = threadIdx.x;
  __shared__ float u2[D];
  __shared__ float lg[256];
  __shared__ float red[256];
  u2[tid] = wbuf[tid*BB + b]*mmbuf[tid*BB + b] + wbuf[(D + tid)*BB + b];
  __syncthreads();
  float logit = -INFINITY;
  if (tid < NN){
    float c[8];
    #pragma unroll
    for (int u = 0; u < 8; u++) c[u] = 0.f;
    if (isbf){
      const u16* kb = (const u16*)kmat + (size_t)b*D*NN + tid;
      for (int d = 0; d < D; d += 8){
        #pragma unroll
        for (int u = 0; u < 8; u++) c[u] += u2[d+u]*bf2f(kb[(size_t)(d+u)*NN]);
      }
    } else {
      const float* kb = (const float*)kmat + (size_t)b*D*NN + tid;
      for (int d = 0; d < D; d += 8){
        #pragma unroll
        for (int u = 0; u < 8; u++) c[u] += u2[d+u]*kb[(size_t)(d+u)*NN];
      }
    }
    logit = (((c[0]+c[1]) + (c[2]+c[3])) + ((c[4]+c[5]) + (c[6]+c[7])));
  }
  if (tid < 256){ lg[tid] = logit; red[tid] = logit; }
  __syncthreads();
  for (int off = 128; off; off >>= 1){ if (tid < off) red[tid] = fmaxf(red[tid], red[tid+off]); __syncthreads(); }
  float M = red[0];
  __syncthreads();
  if (tid < 256){ float e = (tid < NN) ? __expf(lg[tid] - M) : 0.f; lg[tid] = e; red[tid] = e; }
  __syncthreads();
  for (int off = 128; off; off >>= 1){ if (tid < off) red[tid] += red[tid+off]; __syncthreads(); }
  float inv = 1.f / red[0];
  int lane = tid & 63, wv = tid >> 6;         // 8 waves
  // r-phase: 2 interleaved d per iteration
  for (int i = 0; i < 32; i++){
    int dA = wv + i*16, dB = dA + 8;
    float p, qv;
    if (isbf){
      const u16* krA = (const u16*)kmat + (size_t)b*D*NN + (size_t)dA*NN;
      const u16* krB = (const u16*)kmat + (size_t)b*D*NN + (size_t)dB*NN;
      p  = lg[lane]*bf2f(krA[lane]) + lg[lane+64]*bf2f(krA[lane+64]) + lg[lane+128]*bf2f(krA[lane+128]);
      qv = lg[lane]*bf2f(krB[lane]) + lg[lane+64]*bf2f(krB[lane+64]) + lg[lane+128]*bf2f(krB[lane+128]);
      if (lane < NN - 192){
        p  += lg[lane+192]*bf2f(krA[lane+192]);
        qv += lg[lane+192]*bf2f(krB[lane+192]);
      }
    } else {
      const float* krA = (const float*)kmat + (size_t)b*D*NN + (size_t)dA*NN;
      const float* krB = (const float*)kmat + (size_t)b*D*NN + (size_t)dB*NN;
      p  = lg[lane]*krA[lane] + lg[lane+64]*krA[lane+64] + lg[lane+128]*krA[lane+128];
      qv = lg[lane]*krB[lane] + lg[lane+64]*krB[lane+64] + lg[lane+128]*krB[lane+128];
      if (lane < NN - 192){
        p  += lg[lane+192]*krA[lane+192];
        qv += lg[lane+192]*krB[lane+192];
      }
    }
    #pragma unroll
    for (int off = 32; off; off >>= 1){
      p  += __shfl_down(p , off, 64);
      qv += __shfl_down(qv, off, 64);
    }
    if (lane == 0){
      act_cur[dA*BB + b] = p  * inv;
      act_cur[dB*BB + b] = qv * inv;
    }
  }
}

// ---------------- K_G3: m, mm_next, u_next (atomic K-split gemvs) ----------------
__global__ __launch_bounds__(256) void k_G3(const float* act_cur, const float* cbuf,
                                            const float* Wwcf, const float* WrmABf, const float* W1f,
                                            float* act_nxt, float* mm_nxt, float* u_nxt, int t){
  int bk = blockIdx.x, tid = threadIdx.x;
  int b = tid & 127;
  int ih = __builtin_amdgcn_readfirstlane(tid >> 7);
  if (bk < 128){
    int it = bk >> 2, kc = bk & 3;
    int i0 = it*16 + ih*8;
    float acc[8] = {0.f,0.f,0.f,0.f,0.f,0.f,0.f,0.f};
    int e0 = kc*256;
    for (int e = e0; e < e0 + 256; e += 4){
      float av[4];
      #pragma unroll
      for (int u = 0; u < 4; u++) av[u] = act_cur[(e+u)*BB + b];
      #pragma unroll
      for (int u = 0; u < 4; u++){
        float4 w0 = *(const float4*)(Wwcf + (size_t)(e+u)*D + i0);
        float4 w1 = *(const float4*)(Wwcf + (size_t)(e+u)*D + i0 + 4);
        acc[0]+=av[u]*w0.x; acc[1]+=av[u]*w0.y; acc[2]+=av[u]*w0.z; acc[3]+=av[u]*w0.w;
        acc[4]+=av[u]*w1.x; acc[5]+=av[u]*w1.y; acc[6]+=av[u]*w1.z; acc[7]+=av[u]*w1.w;
      }
    }
    #pragma unroll
    for (int kk = 0; kk < 8; kk++) atomicAdd(&act_nxt[(D + i0 + kk)*BB + b], acc[kk]);
  } else if (bk < 256){
    if (t == TT-1) return;
    int l = bk - 128;
    int it = l >> 2, kc = l & 3;
    int i0 = it*16 + ih*8;
    float acc[8] = {0.f,0.f,0.f,0.f,0.f,0.f,0.f,0.f};
    int e0 = kc*256;
    for (int e = e0; e < e0 + 256; e += 4){
      float av[4];
      #pragma unroll
      for (int u = 0; u < 4; u++) av[u] = act_cur[(e+u)*BB + b];
      #pragma unroll
      for (int u = 0; u < 4; u++){
        float4 w0 = *(const float4*)(WrmABf + (size_t)(e+u)*D + i0);
        float4 w1 = *(const float4*)(WrmABf + (size_t)(e+u)*D + i0 + 4);
        acc[0]+=av[u]*w0.x; acc[1]+=av[u]*w0.y; acc[2]+=av[u]*w0.z; acc[3]+=av[u]*w0.w;
        acc[4]+=av[u]*w1.x; acc[5]+=av[u]*w1.y; acc[6]+=av[u]*w1.z; acc[7]+=av[u]*w1.w;
      }
    }
    #pragma unroll
    for (int kk = 0; kk < 8; kk++) atomicAdd(&mm_nxt[(i0 + kk)*BB + b], acc[kk]);
  } else {
    if (t == TT-1) return;
    int l = bk - 256;
    int it = l >> 1, kc = l & 1;
    int j0 = it*16 + ih*8;
    float acc[8] = {0.f,0.f,0.f,0.f,0.f,0.f,0.f,0.f};
    int e0 = kc*256;
    for (int e = e0; e < e0 + 256; e += 4){
      float av[4];
      #pragma unroll
      for (int u = 0; u < 4; u++) av[u] = cbuf[(e+u)*BB + b];
      #pragma unroll
      for (int u = 0; u < 4; u++){
        float4 w0 = *(const float4*)(W1f + (size_t)(e+u)*D + j0);
        float4 w1 = *(const float4*)(W1f + (size_t)(e+u)*D + j0 + 4);
        acc[0]+=av[u]*w0.x; acc[1]+=av[u]*w0.y; acc[2]+=av[u]*w0.z; acc[3]+=av[u]*w0.w;
        acc[4]+=av[u]*w1.x; acc[5]+=av[u]*w1.y; acc[6]+=av[u]*w1.z; acc[7]+=av[u]*w1.w;
      }
    }
    #pragma unroll
    for (int kk = 0; kk < 8; kk++) atomicAdd(&u_nxt[(j0 + kk)*BB + b], acc[kk]);
  }
}

// ---------------- K_out: m[i,b] fp32 -> out[b,i] (bf16 or f32) ----------------
__global__ __launch_bounds__(256) void k_out(const float* act_fin, void* out, const int* flag){
  const int isbf = *flag;
  __shared__ float lds[32][33];
  int bk = blockIdx.x;                        // 64 = 16 i-tiles * 4 b-tiles
  int it = bk >> 2, bt = bk & 3;
  int tx = threadIdx.x & 31, ty = threadIdx.x >> 5;
  #pragma unroll
  for (int kk = 0; kk < 4; kk++){
    int i = it*32 + ty + kk*8;
    lds[tx][ty + kk*8] = act_fin[(D + i)*BB + bt*32 + tx];
  }
  __syncthreads();
  if (isbf){
    __hip_bfloat16* o = (__hip_bfloat16*)out;
    #pragma unroll
    for (int kk = 0; kk < 4; kk++){
      int bb = bt*32 + ty + kk*8;
      o[(size_t)bb*D + it*32 + tx] = __float2bfloat16(lds[ty + kk*8][tx]);
    }
  } else {
    float* o = (float*)out;
    #pragma unroll
    for (int kk = 0; kk < 4; kk++){
      int bb = bt*32 + ty + kk*8;
      o[(size_t)bb*D + it*32 + tx] = lds[ty + kk*8][tx];
    }
  }
}

extern "C" void kernel_launch(void* const* d_in, const int* in_sizes, int n_in,
                              void* d_out, int out_size, void* d_ws, size_t ws_size,
                              hipStream_t stream){
  const void* ctx  = d_in[0];
  const void* q    = d_in[1];
  const void* kmat = d_in[2];
  const void* mem0 = d_in[3];
  const void* ctrl0= d_in[4];
  const void* Wp   = d_in[5];
  const void* bp   = d_in[6];
  const void* Wcq  = d_in[7];
  const void* bcq  = d_in[8];
  const void* Wca  = d_in[9];
  const void* Wrm  = d_in[11];
  const void* brm  = d_in[12];
  const void* Wrc  = d_in[13];
  const void* Wra  = d_in[15];
  const void* Wwc  = d_in[17];
  const void* bwc  = d_in[18];

  float* W      = (float*)d_ws;
  float* qT     = W;
  float* P      = W + 131072;
  float* pp2    = W + 917504;
  float* W1f    = W + 1703936;
  float* W2f    = W + 1966080;
  float* Wwcf   = W + 2490368;
  float* WrmTf  = W + 3014656;
  float* WrmABf = W + 3276800;
  float* bmm    = W + 3801088;
  float* ubuf   = W + 3801600;   // 2 x 65536
  float* cbuf   = W + 3932672;
  float* wbuf   = W + 3998208;
  float* mmbuf  = W + 4129280;   // 2 x 65536
  float* actb   = W + 4260352;   // 2 x 131072
  int*   flag   = (int*)(W + 4522496);
  float* ubase  = W + 4522560;   // 512
  float* mmb    = W + 4523072;   // 512

  hipLaunchKernelGGL(k_detect, dim3(1), dim3(256), 0, stream, (const u16*)ctx, flag);
  hipLaunchKernelGGL(k_prep1, dim3(1216), dim3(256), 0, stream,
                     q, Wcq, Wca, Wwc, Wrm, Wrc, Wra, qT, W1f, Wwcf, WrmTf, W2f, flag);
  hipLaunchKernelGGL(k_P,    dim3(768), dim3(256), 0, stream, qT, Wp, bp, P, flag);
  hipLaunchKernelGGL(k_pp2,  dim3(768), dim3(256), 0, stream, P, Wcq, bcq, Wca, pp2, flag);
  hipLaunchKernelGGL(k_comp, dim3(514), dim3(256), 0, stream, WrmTf, Wwc, Wrm, bwc, brm, WrmABf, bmm, flag);
  hipLaunchKernelGGL(k_initA, dim3(32), dim3(256), 0, stream,
                     ctrl0, mem0, Wcq, Wca, Wrm, brm, ubase, mmb, flag);
  hipLaunchKernelGGL(k_initB, dim3(96), dim3(256), 0, stream,
                     ubase, mmb, mem0, pp2, ubuf, mmbuf, actb, flag);

  for (int t = 0; t < TT; t++){
    int cur = t & 1, nxt = 1 - cur;
    hipLaunchKernelGGL(k_A1, dim3(136), dim3(512), 0, stream,
                       ctx, ubuf + cur*65536, cbuf, wbuf, flag);
    hipLaunchKernelGGL(k_G2, dim3(304), dim3(256), 0, stream,
                       cbuf, W2f, wbuf,
                       pp2 + ((t+1 < TT) ? (t+1)*65536 : 0), ubuf + nxt*65536,
                       bmm, mmbuf + nxt*65536,
                       bwc, actb + nxt*131072, t, flag);
    hipLaunchKernelGGL(k_A2, dim3(128), dim3(512), 0, stream,
                       kmat, wbuf, mmbuf + cur*65536, actb + cur*131072, flag);
    hipLaunchKernelGGL(k_G3, dim3(320), dim3(256), 0, stream,
                       actb + cur*131072, cbuf, Wwcf, WrmABf, W1f,
                       actb + nxt*131072, mmbuf + nxt*65536, ubuf + nxt*65536, t);
  }
  hipLaunchKernelGGL(k_out, dim3(64), dim3(256), 0, stream, actb, d_out, flag);
}

// Round 5
// 1527.700 us; speedup vs baseline: 1.6331x; 1.0851x over previous
//
#include <hip/hip_runtime.h>
#include <hip/hip_bf16.h>
#include <cstdint>

#define D  512
#define D2 1024
#define BB 128
#define SS 128
#define NN 196
#define TT 12

typedef unsigned short u16;

__device__ __forceinline__ float bf2f(u16 h){
  union { unsigned int u; float f; } v; v.u = ((unsigned int)h) << 16; return v.f;
}

__device__ __forceinline__ float LDX(const void* p, size_t i, int isbf){
  if (isbf) return bf2f(((const u16*)p)[i]);
  return ((const float*)p)[i];
}

__device__ __forceinline__ float4 LD4(const void* p, size_t i, int isbf){
  if (isbf){
    ushort4 w = *(const ushort4*)((const u16*)p + i);
    return make_float4(bf2f(w.x), bf2f(w.y), bf2f(w.z), bf2f(w.w));
  }
  return *(const float4*)((const float*)p + i);
}

__device__ __forceinline__ float2 LD2(const void* p, size_t i, int isbf){
  if (isbf){
    ushort2 w = *(const ushort2*)((const u16*)p + i);
    return make_float2(bf2f(w.x), bf2f(w.y));
  }
  return *(const float2*)((const float*)p + i);
}

// ---------------- detect input dtype from ctx bit patterns ----------------
__global__ __launch_bounds__(256) void k_detect(const u16* ctx, int* flag){
  __shared__ int cnt;
  if (threadIdx.x == 0) cnt = 0;
  __syncthreads();
  int bad = 0;
  for (int i = threadIdx.x; i < 8192; i += 256){
    int e = (ctx[i] >> 7) & 0xFF;
    if (e == 0xFF || (e != 0 && (e < 90 || e > 160))) bad++;
  }
  atomicAdd(&cnt, bad);
  __syncthreads();
  if (threadIdx.x == 0) *flag = (cnt > 100) ? 0 : 1;   // 1 = bf16, 0 = fp32
}

// ---------------- prep1: transposes / scaled copies of weights ----------------
__global__ __launch_bounds__(256) void k_prep1(const void* q, const void* Wcq, const void* Wca,
      const void* Wwc, const void* Wrm, const void* Wrc, const void* Wra,
      float* qT, float* W1f, float* Wwcf, float* WrmTf, float* W2f, const int* flag){
  const int isbf = *flag;
  __shared__ float lds[32][33];
  int bk = blockIdx.x, tid = threadIdx.x;
  int tx = tid & 31, ty = tid >> 5;
  if (bk >= 1152){
    int l = bk - 1152;
    if (isbf){
      const u16* w = (const u16*)Wrc; const u16* s = (const u16*)Wra;
      for (int idx = l*256 + tid; idx < 524288; idx += 64*256)
        W2f[idx] = bf2f(w[idx]) * bf2f(s[idx >> 10]);
    } else {
      const float* w = (const float*)Wrc; const float* s = (const float*)Wra;
      for (int idx = l*256 + tid; idx < 524288; idx += 64*256)
        W2f[idx] = w[idx] * s[idx >> 10];
    }
    return;
  }
  const void* in = nullptr; const void* scale = nullptr; float* out = nullptr;
  int ld = 0, R = 0, tR = 0, tC = 0;
  if (bk < 128)      { in = q;   ld = 1024; R = 128; out = qT;    tR = bk & 3;  tC = bk >> 2; }
  else if (bk < 384) { int l = bk - 128; in = Wcq; ld = 1024; R = 512; out = W1f;  scale = Wca; tR = l & 15; tC = l >> 4; }
  else if (bk < 896) { int l = bk - 384; in = Wwc; ld = 1024; R = 512; out = Wwcf; tR = l & 15; tC = l >> 4; }
  else               { int l = bk - 896; in = Wrm; ld = 512;  R = 512; out = WrmTf;tR = l & 15; tC = l >> 4; }
  int r0 = tR*32, c0 = tC*32;
  #pragma unroll
  for (int kk = 0; kk < 4; kk++){
    int r = r0 + ty + kk*8;
    float v = LDX(in, (size_t)r*ld + c0 + tx, isbf);
    if (scale) v *= LDX(scale, r, isbf);
    lds[tx][ty + kk*8] = v;
  }
  __syncthreads();
  #pragma unroll
  for (int kk = 0; kk < 4; kk++){
    int oc = ty + kk*8;
    out[(size_t)(c0 + oc)*R + r0 + tx] = lds[oc][tx];
  }
}

// ---------------- K_P: P[t,e,b] = sum_x qT[x,b]*Wp[t,e,x] + bp[t,e] ----------------
// 1536 blocks = 12t * 128et, 2 outputs/thread
__global__ __launch_bounds__(256) void k_P(const float* qT, const void* Wp, const void* bp,
                                           float* P, const int* flag){
  const int isbf = *flag;
  int bk = blockIdx.x;
  int t = bk >> 7, et = bk & 127;
  int tid = threadIdx.x;
  int b = tid & 127;
  int ih = __builtin_amdgcn_readfirstlane(tid >> 7);
  int e0 = et*4 + ih*2;
  float acc[2];
  #pragma unroll
  for (int kk = 0; kk < 2; kk++) acc[kk] = LDX(bp, t*D + e0 + kk, isbf);
  size_t wo = (size_t)(t*D + e0)*D2;
  if (isbf){
    const u16* wb = (const u16*)Wp + wo;
    for (int x = 0; x < D2; x += 8){
      float a[8];
      #pragma unroll
      for (int u = 0; u < 8; u++) a[u] = qT[(x+u)*BB + b];
      #pragma unroll
      for (int kk = 0; kk < 2; kk++){
        ushort4 w0 = *(const ushort4*)(wb + kk*D2 + x);
        ushort4 w1 = *(const ushort4*)(wb + kk*D2 + x + 4);
        acc[kk] += a[0]*bf2f(w0.x) + a[1]*bf2f(w0.y) + a[2]*bf2f(w0.z) + a[3]*bf2f(w0.w)
                 + a[4]*bf2f(w1.x) + a[5]*bf2f(w1.y) + a[6]*bf2f(w1.z) + a[7]*bf2f(w1.w);
      }
    }
  } else {
    const float* wb = (const float*)Wp + wo;
    for (int x = 0; x < D2; x += 8){
      float a[8];
      #pragma unroll
      for (int u = 0; u < 8; u++) a[u] = qT[(x+u)*BB + b];
      #pragma unroll
      for (int kk = 0; kk < 2; kk++){
        float4 w0 = *(const float4*)(wb + kk*D2 + x);
        float4 w1 = *(const float4*)(wb + kk*D2 + x + 4);
        acc[kk] += a[0]*w0.x + a[1]*w0.y + a[2]*w0.z + a[3]*w0.w
                 + a[4]*w1.x + a[5]*w1.y + a[6]*w1.z + a[7]*w1.w;
      }
    }
  }
  #pragma unroll
  for (int kk = 0; kk < 2; kk++) P[(size_t)(t*D + e0 + kk)*BB + b] = acc[kk];
}

// ---------------- K_pp2: pp2[t,j,b] = (sum_e P[t,e,b]*Wcq[j,D+e] + bcq[j]) * Wca[j] ----------------
// 1536 blocks = 12t * 128jt, 2 outputs/thread
__global__ __launch_bounds__(256) void k_pp2(const float* P, const void* Wcq, const void* bcq,
                                             const void* Wca, float* pp2, const int* flag){
  const int isbf = *flag;
  int bk = blockIdx.x;
  int t = bk >> 7, jt = bk & 127;
  int tid = threadIdx.x;
  int b = tid & 127;
  int ih = __builtin_amdgcn_readfirstlane(tid >> 7);
  int j0 = jt*4 + ih*2;
  float acc[2];
  #pragma unroll
  for (int kk = 0; kk < 2; kk++) acc[kk] = LDX(bcq, j0 + kk, isbf);
  if (isbf){
    const u16* w = (const u16*)Wcq;
    for (int e = 0; e < D; e += 8){
      float a[8];
      #pragma unroll
      for (int u = 0; u < 8; u++) a[u] = P[(size_t)(t*D + e + u)*BB + b];
      #pragma unroll
      for (int kk = 0; kk < 2; kk++){
        ushort4 w0 = *(const ushort4*)(w + (size_t)(j0+kk)*D2 + D + e);
        ushort4 w1 = *(const ushort4*)(w + (size_t)(j0+kk)*D2 + D + e + 4);
        acc[kk] += a[0]*bf2f(w0.x) + a[1]*bf2f(w0.y) + a[2]*bf2f(w0.z) + a[3]*bf2f(w0.w)
                 + a[4]*bf2f(w1.x) + a[5]*bf2f(w1.y) + a[6]*bf2f(w1.z) + a[7]*bf2f(w1.w);
      }
    }
  } else {
    const float* w = (const float*)Wcq;
    for (int e = 0; e < D; e += 8){
      float a[8];
      #pragma unroll
      for (int u = 0; u < 8; u++) a[u] = P[(size_t)(t*D + e + u)*BB + b];
      #pragma unroll
      for (int kk = 0; kk < 2; kk++){
        float4 w0 = *(const float4*)(w + (size_t)(j0+kk)*D2 + D + e);
        float4 w1 = *(const float4*)(w + (size_t)(j0+kk)*D2 + D + e + 4);
        acc[kk] += a[0]*w0.x + a[1]*w0.y + a[2]*w0.z + a[3]*w0.w
                 + a[4]*w1.x + a[5]*w1.y + a[6]*w1.z + a[7]*w1.w;
      }
    }
  }
  #pragma unroll
  for (int kk = 0; kk < 2; kk++)
    pp2[(size_t)(t*D + j0 + kk)*BB + b] = acc[kk] * LDX(Wca, j0 + kk, isbf);
}

// ---------------- K_comp: WrmABf[e,i] = sum_d Wrm[i,d]*Wwc[d,e]; bmm[i] ----------------
// 1024 gemv blocks: et(128) x ic(8), i-lane 64-wide, 2 outputs; + 2 bmm blocks
__global__ __launch_bounds__(256) void k_comp(const float* WrmTf, const void* Wwc, const void* Wrm,
                                              const void* bwc, const void* brm,
                                              float* WrmABf, float* bmm, const int* flag){
  const int isbf = *flag;
  int bk = blockIdx.x, tid = threadIdx.x;
  if (bk < 1024){
    int et = bk >> 3, ic = bk & 7;
    int i = ic*64 + (tid & 63);
    int ih = __builtin_amdgcn_readfirstlane(tid >> 6);   // 0..3
    int e0 = et*8 + ih*2;
    float acc[2] = {0.f, 0.f};
    for (int d = 0; d < D; d += 8){
      float av[8];
      #pragma unroll
      for (int u = 0; u < 8; u++) av[u] = WrmTf[(size_t)(d+u)*D + i];
      #pragma unroll
      for (int u = 0; u < 8; u++){
        float2 wv = LD2(Wwc, (size_t)(d+u)*D2 + e0, isbf);
        acc[0] += av[u]*wv.x; acc[1] += av[u]*wv.y;
      }
    }
    #pragma unroll
    for (int kk = 0; kk < 2; kk++) WrmABf[(size_t)(e0+kk)*D + i] = acc[kk];
  } else {
    int i = (bk - 1024)*256 + tid;
    float a0 = LDX(brm, i, isbf), a1 = 0.f, a2 = 0.f, a3 = 0.f;
    for (int d = 0; d < D; d += 4){
      a0 += LDX(bwc, d  , isbf) * LDX(Wrm, (size_t)i*D + d  , isbf);
      a1 += LDX(bwc, d+1, isbf) * LDX(Wrm, (size_t)i*D + d+1, isbf);
      a2 += LDX(bwc, d+2, isbf) * LDX(Wrm, (size_t)i*D + d+2, isbf);
      a3 += LDX(bwc, d+3, isbf) * LDX(Wrm, (size_t)i*D + d+3, isbf);
    }
    bmm[i] = (a0 + a1) + (a2 + a3);
  }
}

// ---------------- K_initA: b-independent base vectors via K-split reduction ----------------
__global__ __launch_bounds__(256) void k_initA(const void* ctrl0, const void* mem0,
                                               const void* Wcq, const void* Wca,
                                               const void* Wrm, const void* brm,
                                               float* ubase, float* mmb, const int* flag){
  const int isbf = *flag;
  int bk = blockIdx.x, tid = threadIdx.x;
  int lane = tid & 63, w = tid >> 6;
  int grp = lane >> 3, k = lane & 7;
  int isU = (bk < 16);
  int o = (isU ? bk : bk - 16)*32 + w*8 + grp;
  const void* vec = isU ? ctrl0 : mem0;
  const void* mat = isU ? Wcq : Wrm;
  int ld = isU ? D2 : D;
  float acc = 0.f;
  #pragma unroll 4
  for (int it = 0; it < 16; it++){
    int d = it*32 + k*4;
    float4 v = LD4(vec, d, isbf);
    float4 m = LD4(mat, (size_t)o*ld + d, isbf);
    acc += v.x*m.x + v.y*m.y + v.z*m.z + v.w*m.w;
  }
  acc += __shfl_xor(acc, 1, 64);
  acc += __shfl_xor(acc, 2, 64);
  acc += __shfl_xor(acc, 4, 64);
  if (k == 0){
    if (isU) ubase[o] = acc * LDX(Wca, o, isbf);
    else     mmb[o]   = acc + LDX(brm, o, isbf);
  }
}

// ---------------- K_initB: broadcast u0, mm0, m_{-1}, zero wbuf ----------------
__global__ __launch_bounds__(256) void k_initB(const float* ubase, const float* mmb,
                                               const void* mem0, const float* pp2,
                                               float* u0, float* mm0, float* act0, float* wbuf,
                                               const int* flag){
  const int isbf = *flag;
  for (int idx = blockIdx.x*256 + threadIdx.x; idx < 3*D*BB + D2*BB; idx += 160*256){
    if (idx < D*BB)            u0[idx] = ubase[idx >> 7] + pp2[idx];
    else if (idx < 2*D*BB)   { int x = idx - D*BB;   mm0[x] = mmb[x >> 7]; }
    else if (idx < 3*D*BB)   { int x = idx - 2*D*BB; act0[D*BB + x] = LDX(mem0, x >> 7, isbf); }
    else                       wbuf[idx - 3*D*BB] = 0.f;
  }
}

// ---------------- K_A1: ctx attention (per-batch block, 512 thr) ----------------
__global__ __launch_bounds__(512) void k_A1(const void* ctx, const float* ubuf, float* cbuf,
                                            const int* flag){
  int tid = threadIdx.x;
  const int isbf = *flag;
  __shared__ float lg[SS];
  __shared__ float red[128];
  int b = blockIdx.x;
  int lane = tid & 63, wv = tid >> 6;         // 8 waves
  float ur[8];
  #pragma unroll
  for (int kk = 0; kk < 8; kk++) ur[kk] = ubuf[(lane*8 + kk)*BB + b];
  for (int s = wv; s < SS; s += 16){
    int s2 = s + 8;
    float dotA, dotB;
    if (isbf){
      const u16* crowA = (const u16*)ctx + ((size_t)(b*SS + s ))*D + lane*8;
      const u16* crowB = (const u16*)ctx + ((size_t)(b*SS + s2))*D + lane*8;
      ushort4 a0 = *(const ushort4*)crowA, a1 = *(const ushort4*)(crowA + 4);
      ushort4 b0 = *(const ushort4*)crowB, b1 = *(const ushort4*)(crowB + 4);
      dotA = ur[0]*bf2f(a0.x) + ur[1]*bf2f(a0.y) + ur[2]*bf2f(a0.z) + ur[3]*bf2f(a0.w)
           + ur[4]*bf2f(a1.x) + ur[5]*bf2f(a1.y) + ur[6]*bf2f(a1.z) + ur[7]*bf2f(a1.w);
      dotB = ur[0]*bf2f(b0.x) + ur[1]*bf2f(b0.y) + ur[2]*bf2f(b0.z) + ur[3]*bf2f(b0.w)
           + ur[4]*bf2f(b1.x) + ur[5]*bf2f(b1.y) + ur[6]*bf2f(b1.z) + ur[7]*bf2f(b1.w);
    } else {
      const float* crowA = (const float*)ctx + ((size_t)(b*SS + s ))*D + lane*8;
      const float* crowB = (const float*)ctx + ((size_t)(b*SS + s2))*D + lane*8;
      float4 a0 = *(const float4*)crowA, a1 = *(const float4*)(crowA + 4);
      float4 b0 = *(const float4*)crowB, b1 = *(const float4*)(crowB + 4);
      dotA = ur[0]*a0.x + ur[1]*a0.y + ur[2]*a0.z + ur[3]*a0.w
           + ur[4]*a1.x + ur[5]*a1.y + ur[6]*a1.z + ur[7]*a1.w;
      dotB = ur[0]*b0.x + ur[1]*b0.y + ur[2]*b0.z + ur[3]*b0.w
           + ur[4]*b1.x + ur[5]*b1.y + ur[6]*b1.z + ur[7]*b1.w;
    }
    #pragma unroll
    for (int off = 32; off; off >>= 1){
      dotA += __shfl_down(dotA, off, 64);
      dotB += __shfl_down(dotB, off, 64);
    }
    if (lane == 0){ lg[s] = dotA; lg[s2] = dotB; }
  }
  __syncthreads();
  if (tid < 128) red[tid] = lg[tid];
  __syncthreads();
  for (int off = 64; off; off >>= 1){ if (tid < off) red[tid] = fmaxf(red[tid], red[tid+off]); __syncthreads(); }
  float M = red[0];
  __syncthreads();
  if (tid < 128){ float e = __expf(lg[tid] - M); lg[tid] = e; red[tid] = e; }
  __syncthreads();
  for (int off = 64; off; off >>= 1){ if (tid < off) red[tid] += red[tid+off]; __syncthreads(); }
  float inv = 1.f / red[0];
  int d = tid;
  float a[8];
  #pragma unroll
  for (int u = 0; u < 8; u++) a[u] = 0.f;
  if (isbf){
    const u16* cb = (const u16*)ctx + ((size_t)b*SS)*D + d;
    for (int s = 0; s < SS; s += 8){
      #pragma unroll
      for (int u = 0; u < 8; u++) a[u] += lg[s+u]*bf2f(cb[(size_t)(s+u)*D]);
    }
  } else {
    const float* cb = (const float*)ctx + ((size_t)b*SS)*D + d;
    for (int s = 0; s < SS; s += 8){
      #pragma unroll
      for (int u = 0; u < 8; u++) a[u] += lg[s+u]*cb[(size_t)(s+u)*D];
    }
  }
  cbuf[d*BB + b] = (((a[0]+a[1]) + (a[2]+a[3])) + ((a[4]+a[5]) + (a[6]+a[7]))) * inv;
}

// ---------------- K_G2: w += c@W2f (atomic, K-split x4) + preload next-step accumulators ----------------
__global__ __launch_bounds__(256) void k_G2(const float* cbuf, const float* W2f, float* wbuf,
                                            const float* pp2_next, float* u_nxt,
                                            const float* bmm, float* mm_nxt,
                                            const void* bwc, float* act_nxt, int t, const int* flag){
  int bk = blockIdx.x, tid = threadIdx.x;
  if (bk < 512){
    int et = bk >> 2, kc = bk & 3;
    int b = tid & 127;
    int ih = __builtin_amdgcn_readfirstlane(tid >> 7);
    int e0 = et*8 + ih*4;
    float acc[4] = {0.f, 0.f, 0.f, 0.f};
    int j0 = kc*128;
    for (int j = j0; j < j0 + 128; j += 8){
      float av[8];
      #pragma unroll
      for (int u = 0; u < 8; u++) av[u] = cbuf[(j+u)*BB + b];
      #pragma unroll
      for (int u = 0; u < 8; u++){
        float4 wv = *(const float4*)(W2f + (size_t)(j+u)*D2 + e0);
        acc[0] += av[u]*wv.x; acc[1] += av[u]*wv.y;
        acc[2] += av[u]*wv.z; acc[3] += av[u]*wv.w;
      }
    }
    #pragma unroll
    for (int kk = 0; kk < 4; kk++) atomicAdd(&wbuf[(e0+kk)*BB + b], acc[kk]);
  } else if (bk < 528){
    if (t < TT-1)
      for (int x = (bk-512)*256 + tid; x < D*BB; x += 16*256) u_nxt[x] = pp2_next[x];
  } else if (bk < 544){
    if (t < TT-1)
      for (int x = (bk-528)*256 + tid; x < D*BB; x += 16*256) mm_nxt[x] = bmm[x >> 7];
  } else {
    const int isbf = *flag;
    if (isbf){
      const u16* w = (const u16*)bwc;
      for (int x = (bk-544)*256 + tid; x < D*BB; x += 16*256) act_nxt[D*BB + x] = bf2f(w[x >> 7]);
    } else {
      const float* w = (const float*)bwc;
      for (int x = (bk-544)*256 + tid; x < D*BB; x += 16*256) act_nxt[D*BB + x] = w[x >> 7];
    }
  }
}

// ---------------- K_A2: k attention (per-batch block, 512 thr) -> r into act_cur ----------------
__global__ __launch_bounds__(512) void k_A2(const void* kmat, const float* wbuf,
                                            const float* mmbuf, float* act_cur, const int* flag){
  const int isbf = *flag;
  int b = blockIdx.x, tid = threadIdx.x;
  __shared__ float u2[D];
  __shared__ float lg[256];
  __shared__ float red[256];
  __shared__ float ps[2][256];
  u2[tid] = wbuf[tid*BB + b]*mmbuf[tid*BB + b] + wbuf[(D + tid)*BB + b];
  __syncthreads();
  // logits: d-split x2 across all 512 threads
  {
    int half = tid >> 8;                 // 0/1
    int n = tid & 255;
    float part = 0.f;
    if (n < NN){
      float c[8];
      #pragma unroll
      for (int u = 0; u < 8; u++) c[u] = 0.f;
      int d0 = half*256;
      if (isbf){
        const u16* kb = (const u16*)kmat + (size_t)b*D*NN + n;
        for (int dd = 0; dd < 256; dd += 8){
          #pragma unroll
          for (int u = 0; u < 8; u++) c[u] += u2[d0+dd+u]*bf2f(kb[(size_t)(d0+dd+u)*NN]);
        }
      } else {
        const float* kb = (const float*)kmat + (size_t)b*D*NN + n;
        for (int dd = 0; dd < 256; dd += 8){
          #pragma unroll
          for (int u = 0; u < 8; u++) c[u] += u2[d0+dd+u]*kb[(size_t)(d0+dd+u)*NN];
        }
      }
      part = (((c[0]+c[1]) + (c[2]+c[3])) + ((c[4]+c[5]) + (c[6]+c[7])));
    }
    ps[half][n] = part;
  }
  __syncthreads();
  if (tid < 256){
    float logit = (tid < NN) ? (ps[0][tid] + ps[1][tid]) : -INFINITY;
    lg[tid] = logit; red[tid] = logit;
  }
  __syncthreads();
  for (int off = 128; off; off >>= 1){ if (tid < off) red[tid] = fmaxf(red[tid], red[tid+off]); __syncthreads(); }
  float M = red[0];
  __syncthreads();
  if (tid < 256){ float e = (tid < NN) ? __expf(lg[tid] - M) : 0.f; lg[tid] = e; red[tid] = e; }
  __syncthreads();
  for (int off = 128; off; off >>= 1){ if (tid < off) red[tid] += red[tid+off]; __syncthreads(); }
  float inv = 1.f / red[0];
  int lane = tid & 63, wv = tid >> 6;         // 8 waves
  for (int i = 0; i < 32; i++){
    int dA = wv + i*16, dB = dA + 8;
    float p, qv;
    if (isbf){
      const u16* krA = (const u16*)kmat + (size_t)b*D*NN + (size_t)dA*NN;
      const u16* krB = (const u16*)kmat + (size_t)b*D*NN + (size_t)dB*NN;
      p  = lg[lane]*bf2f(krA[lane]) + lg[lane+64]*bf2f(krA[lane+64]) + lg[lane+128]*bf2f(krA[lane+128]);
      qv = lg[lane]*bf2f(krB[lane]) + lg[lane+64]*bf2f(krB[lane+64]) + lg[lane+128]*bf2f(krB[lane+128]);
      if (lane < NN - 192){
        p  += lg[lane+192]*bf2f(krA[lane+192]);
        qv += lg[lane+192]*bf2f(krB[lane+192]);
      }
    } else {
      const float* krA = (const float*)kmat + (size_t)b*D*NN + (size_t)dA*NN;
      const float* krB = (const float*)kmat + (size_t)b*D*NN + (size_t)dB*NN;
      p  = lg[lane]*krA[lane] + lg[lane+64]*krA[lane+64] + lg[lane+128]*krA[lane+128];
      qv = lg[lane]*krB[lane] + lg[lane+64]*krB[lane+64] + lg[lane+128]*krB[lane+128];
      if (lane < NN - 192){
        p  += lg[lane+192]*krA[lane+192];
        qv += lg[lane+192]*krB[lane+192];
      }
    }
    #pragma unroll
    for (int off = 32; off; off >>= 1){
      p  += __shfl_down(p , off, 64);
      qv += __shfl_down(qv, off, 64);
    }
    if (lane == 0){
      act_cur[dA*BB + b] = p  * inv;
      act_cur[dB*BB + b] = qv * inv;
    }
  }
}

// ---------------- K_G3: m, mm_next, u_next (atomic K-split gemvs) + zero wbuf for next step ----------------
__global__ __launch_bounds__(256) void k_G3(const float* act_cur, const float* cbuf,
                                            const float* Wwcf, const float* WrmABf, const float* W1f,
                                            float* act_nxt, float* mm_nxt, float* u_nxt, float* wbuf,
                                            int t){
  int bk = blockIdx.x, tid = threadIdx.x;
  int b = tid & 127;
  int ih = __builtin_amdgcn_readfirstlane(tid >> 7);
  if (bk < 512){
    int ismm = bk >> 8;                        // 0: act path, 1: mm path
    if (ismm && t == TT-1) return;
    int l = bk & 255;
    int it = l >> 3, kc = l & 7;
    int i0 = it*16 + ih*8;
    const float* Wm = ismm ? WrmABf : Wwcf;
    float acc[8] = {0.f,0.f,0.f,0.f,0.f,0.f,0.f,0.f};
    int e0 = kc*128;
    for (int e = e0; e < e0 + 128; e += 8){
      float av[8];
      #pragma unroll
      for (int u = 0; u < 8; u++) av[u] = act_cur[(e+u)*BB + b];
      #pragma unroll
      for (int u = 0; u < 8; u++){
        float4 w0 = *(const float4*)(Wm + (size_t)(e+u)*D + i0);
        float4 w1 = *(const float4*)(Wm + (size_t)(e+u)*D + i0 + 4);
        acc[0]+=av[u]*w0.x; acc[1]+=av[u]*w0.y; acc[2]+=av[u]*w0.z; acc[3]+=av[u]*w0.w;
        acc[4]+=av[u]*w1.x; acc[5]+=av[u]*w1.y; acc[6]+=av[u]*w1.z; acc[7]+=av[u]*w1.w;
      }
    }
    float* dst = ismm ? (mm_nxt + (size_t)i0*BB) : (act_nxt + (size_t)(D + i0)*BB);
    #pragma unroll
    for (int kk = 0; kk < 8; kk++) atomicAdd(dst + (size_t)kk*BB + b, acc[kk]);
  } else if (bk < 640){
    if (t == TT-1) return;
    int l = bk - 512;
    int it = l >> 2, kc = l & 3;
    int j0 = it*16 + ih*8;
    float acc[8] = {0.f,0.f,0.f,0.f,0.f,0.f,0.f,0.f};
    int e0 = kc*128;
    for (int e = e0; e < e0 + 128; e += 8){
      float av[8];
      #pragma unroll
      for (int u = 0; u < 8; u++) av[u] = cbuf[(e+u)*BB + b];
      #pragma unroll
      for (int u = 0; u < 8; u++){
        float4 w0 = *(const float4*)(W1f + (size_t)(e+u)*D + j0);
        float4 w1 = *(const float4*)(W1f + (size_t)(e+u)*D + j0 + 4);
        acc[0]+=av[u]*w0.x; acc[1]+=av[u]*w0.y; acc[2]+=av[u]*w0.z; acc[3]+=av[u]*w0.w;
        acc[4]+=av[u]*w1.x; acc[5]+=av[u]*w1.y; acc[6]+=av[u]*w1.z; acc[7]+=av[u]*w1.w;
      }
    }
    #pragma unroll
    for (int kk = 0; kk < 8; kk++) atomicAdd(&u_nxt[(j0 + kk)*BB + b], acc[kk]);
  } else {
    if (t == TT-1) return;
    for (int x = (bk-640)*256 + tid; x < D2*BB; x += 16*256) wbuf[x] = 0.f;
  }
}

// ---------------- K_out: m[i,b] fp32 -> out[b,i] (bf16 or f32) ----------------
__global__ __launch_bounds__(256) void k_out(const float* act_fin, void* out, const int* flag){
  const int isbf = *flag;
  __shared__ float lds[32][33];
  int bk = blockIdx.x;
  int it = bk >> 2, bt = bk & 3;
  int tx = threadIdx.x & 31, ty = threadIdx.x >> 5;
  #pragma unroll
  for (int kk = 0; kk < 4; kk++){
    int i = it*32 + ty + kk*8;
    lds[tx][ty + kk*8] = act_fin[(D + i)*BB + bt*32 + tx];
  }
  __syncthreads();
  if (isbf){
    __hip_bfloat16* o = (__hip_bfloat16*)out;
    #pragma unroll
    for (int kk = 0; kk < 4; kk++){
      int bb = bt*32 + ty + kk*8;
      o[(size_t)bb*D + it*32 + tx] = __float2bfloat16(lds[ty + kk*8][tx]);
    }
  } else {
    float* o = (float*)out;
    #pragma unroll
    for (int kk = 0; kk < 4; kk++){
      int bb = bt*32 + ty + kk*8;
      o[(size_t)bb*D + it*32 + tx] = lds[ty + kk*8][tx];
    }
  }
}

extern "C" void kernel_launch(void* const* d_in, const int* in_sizes, int n_in,
                              void* d_out, int out_size, void* d_ws, size_t ws_size,
                              hipStream_t stream){
  const void* ctx  = d_in[0];
  const void* q    = d_in[1];
  const void* kmat = d_in[2];
  const void* mem0 = d_in[3];
  const void* ctrl0= d_in[4];
  const void* Wp   = d_in[5];
  const void* bp   = d_in[6];
  const void* Wcq  = d_in[7];
  const void* bcq  = d_in[8];
  const void* Wca  = d_in[9];
  const void* Wrm  = d_in[11];
  const void* brm  = d_in[12];
  const void* Wrc  = d_in[13];
  const void* Wra  = d_in[15];
  const void* Wwc  = d_in[17];
  const void* bwc  = d_in[18];

  float* W      = (float*)d_ws;
  float* qT     = W;
  float* P      = W + 131072;
  float* pp2    = W + 917504;
  float* W1f    = W + 1703936;
  float* W2f    = W + 1966080;
  float* Wwcf   = W + 2490368;
  float* WrmTf  = W + 3014656;
  float* WrmABf = W + 3276800;
  float* bmm    = W + 3801088;
  float* ubuf   = W + 3801600;   // 2 x 65536
  float* cbuf   = W + 3932672;
  float* wbuf   = W + 3998208;
  float* mmbuf  = W + 4129280;   // 2 x 65536
  float* actb   = W + 4260352;   // 2 x 131072
  int*   flag   = (int*)(W + 4522496);
  float* ubase  = W + 4522560;   // 512
  float* mmb    = W + 4523072;   // 512

  hipLaunchKernelGGL(k_detect, dim3(1), dim3(256), 0, stream, (const u16*)ctx, flag);
  hipLaunchKernelGGL(k_prep1, dim3(1216), dim3(256), 0, stream,
                     q, Wcq, Wca, Wwc, Wrm, Wrc, Wra, qT, W1f, Wwcf, WrmTf, W2f, flag);
  hipLaunchKernelGGL(k_P,    dim3(1536), dim3(256), 0, stream, qT, Wp, bp, P, flag);
  hipLaunchKernelGGL(k_pp2,  dim3(1536), dim3(256), 0, stream, P, Wcq, bcq, Wca, pp2, flag);
  hipLaunchKernelGGL(k_comp, dim3(1026), dim3(256), 0, stream, WrmTf, Wwc, Wrm, bwc, brm, WrmABf, bmm, flag);
  hipLaunchKernelGGL(k_initA, dim3(32), dim3(256), 0, stream,
                     ctrl0, mem0, Wcq, Wca, Wrm, brm, ubase, mmb, flag);
  hipLaunchKernelGGL(k_initB, dim3(160), dim3(256), 0, stream,
                     ubase, mmb, mem0, pp2, ubuf, mmbuf, actb, wbuf, flag);

  for (int t = 0; t < TT; t++){
    int cur = t & 1, nxt = 1 - cur;
    hipLaunchKernelGGL(k_A1, dim3(128), dim3(512), 0, stream,
                       ctx, ubuf + cur*65536, cbuf, flag);
    hipLaunchKernelGGL(k_G2, dim3(560), dim3(256), 0, stream,
                       cbuf, W2f, wbuf,
                       pp2 + ((t+1 < TT) ? (t+1)*65536 : 0), ubuf + nxt*65536,
                       bmm, mmbuf + nxt*65536,
                       bwc, actb + nxt*131072, t, flag);
    hipLaunchKernelGGL(k_A2, dim3(128), dim3(512), 0, stream,
                       kmat, wbuf, mmbuf + cur*65536, actb + cur*131072, flag);
    hipLaunchKernelGGL(k_G3, dim3(656), dim3(256), 0, stream,
                       actb + cur*131072, cbuf, Wwcf, WrmABf, W1f,
                       actb + nxt*131072, mmbuf + nxt*65536, ubuf + nxt*65536, wbuf, t);
  }
  hipLaunchKernelGGL(k_out, dim3(64), dim3(256), 0, stream, actb, d_out, flag);
}

// Round 6
// 1345.732 us; speedup vs baseline: 1.8539x; 1.1352x over previous
//
#include <hip/hip_runtime.h>
#include <hip/hip_bf16.h>
#include <cstdint>

#define D  512
#define D2 1024
#define BB 128
#define SS 128
#define NN 196
#define TT 12

typedef unsigned short u16;

__device__ __forceinline__ float bf2f(u16 h){
  union { unsigned int u; float f; } v; v.u = ((unsigned int)h) << 16; return v.f;
}

__device__ __forceinline__ float LDX(const void* p, size_t i, int isbf){
  if (isbf) return bf2f(((const u16*)p)[i]);
  return ((const float*)p)[i];
}

__device__ __forceinline__ float4 LD4(const void* p, size_t i, int isbf){
  if (isbf){
    ushort4 w = *(const ushort4*)((const u16*)p + i);
    return make_float4(bf2f(w.x), bf2f(w.y), bf2f(w.z), bf2f(w.w));
  }
  return *(const float4*)((const float*)p + i);
}

// ---------------- detect input dtype from ctx bit patterns ----------------
__global__ __launch_bounds__(256) void k_detect(const u16* ctx, int* flag){
  __shared__ int cnt;
  if (threadIdx.x == 0) cnt = 0;
  __syncthreads();
  int bad = 0;
  for (int i = threadIdx.x; i < 8192; i += 256){
    int e = (ctx[i] >> 7) & 0xFF;
    if (e == 0xFF || (e != 0 && (e < 90 || e > 160))) bad++;
  }
  atomicAdd(&cnt, bad);
  __syncthreads();
  if (threadIdx.x == 0) *flag = (cnt > 100) ? 0 : 1;   // 1 = bf16, 0 = fp32
}

// ---------------- prep1: transposes / scaled copies of weights ----------------
__global__ __launch_bounds__(256) void k_prep1(const void* q, const void* Wcq, const void* Wca,
      const void* Wwc, const void* Wrm, const void* Wrc, const void* Wra,
      float* qT, float* W1f, float* Wwcf, float* WrmTf, float* W2f, const int* flag){
  const int isbf = *flag;
  __shared__ float lds[32][33];
  int bk = blockIdx.x, tid = threadIdx.x;
  int tx = tid & 31, ty = tid >> 5;
  if (bk >= 1152){
    int l = bk - 1152;
    if (isbf){
      const u16* w = (const u16*)Wrc; const u16* s = (const u16*)Wra;
      for (int idx = l*256 + tid; idx < 524288; idx += 64*256)
        W2f[idx] = bf2f(w[idx]) * bf2f(s[idx >> 10]);
    } else {
      const float* w = (const float*)Wrc; const float* s = (const float*)Wra;
      for (int idx = l*256 + tid; idx < 524288; idx += 64*256)
        W2f[idx] = w[idx] * s[idx >> 10];
    }
    return;
  }
  const void* in = nullptr; const void* scale = nullptr; float* out = nullptr;
  int ld = 0, R = 0, tR = 0, tC = 0;
  if (bk < 128)      { in = q;   ld = 1024; R = 128; out = qT;    tR = bk & 3;  tC = bk >> 2; }
  else if (bk < 384) { int l = bk - 128; in = Wcq; ld = 1024; R = 512; out = W1f;  scale = Wca; tR = l & 15; tC = l >> 4; }
  else if (bk < 896) { int l = bk - 384; in = Wwc; ld = 1024; R = 512; out = Wwcf; tR = l & 15; tC = l >> 4; }
  else               { int l = bk - 896; in = Wrm; ld = 512;  R = 512; out = WrmTf;tR = l & 15; tC = l >> 4; }
  int r0 = tR*32, c0 = tC*32;
  #pragma unroll
  for (int kk = 0; kk < 4; kk++){
    int r = r0 + ty + kk*8;
    float v = LDX(in, (size_t)r*ld + c0 + tx, isbf);
    if (scale) v *= LDX(scale, r, isbf);
    lds[tx][ty + kk*8] = v;
  }
  __syncthreads();
  #pragma unroll
  for (int kk = 0; kk < 4; kk++){
    int oc = ty + kk*8;
    out[(size_t)(c0 + oc)*R + r0 + tx] = lds[oc][tx];
  }
}

// ---------------- K_P: P[t,e,b] = sum_x qT[x,b]*Wp[t,e,x] + bp[t,e] ----------------
__global__ __launch_bounds__(256) void k_P(const float* qT, const void* Wp, const void* bp,
                                           float* P, const int* flag){
  const int isbf = *flag;
  int bk = blockIdx.x;
  int t = bk >> 7, et = bk & 127;
  int tid = threadIdx.x;
  int b = tid & 127;
  int ih = __builtin_amdgcn_readfirstlane(tid >> 7);
  int e0 = et*4 + ih*2;
  float acc[2];
  #pragma unroll
  for (int kk = 0; kk < 2; kk++) acc[kk] = LDX(bp, t*D + e0 + kk, isbf);
  size_t wo = (size_t)(t*D + e0)*D2;
  if (isbf){
    const u16* wb = (const u16*)Wp + wo;
    for (int x = 0; x < D2; x += 8){
      float a[8];
      #pragma unroll
      for (int u = 0; u < 8; u++) a[u] = qT[(x+u)*BB + b];
      #pragma unroll
      for (int kk = 0; kk < 2; kk++){
        ushort4 w0 = *(const ushort4*)(wb + kk*D2 + x);
        ushort4 w1 = *(const ushort4*)(wb + kk*D2 + x + 4);
        acc[kk] += a[0]*bf2f(w0.x) + a[1]*bf2f(w0.y) + a[2]*bf2f(w0.z) + a[3]*bf2f(w0.w)
                 + a[4]*bf2f(w1.x) + a[5]*bf2f(w1.y) + a[6]*bf2f(w1.z) + a[7]*bf2f(w1.w);
      }
    }
  } else {
    const float* wb = (const float*)Wp + wo;
    for (int x = 0; x < D2; x += 8){
      float a[8];
      #pragma unroll
      for (int u = 0; u < 8; u++) a[u] = qT[(x+u)*BB + b];
      #pragma unroll
      for (int kk = 0; kk < 2; kk++){
        float4 w0 = *(const float4*)(wb + kk*D2 + x);
        float4 w1 = *(const float4*)(wb + kk*D2 + x + 4);
        acc[kk] += a[0]*w0.x + a[1]*w0.y + a[2]*w0.z + a[3]*w0.w
                 + a[4]*w1.x + a[5]*w1.y + a[6]*w1.z + a[7]*w1.w;
      }
    }
  }
  #pragma unroll
  for (int kk = 0; kk < 2; kk++) P[(size_t)(t*D + e0 + kk)*BB + b] = acc[kk];
}

// ---------------- K_pp2: pp2[t,j,b] = (sum_e P[t,e,b]*Wcq[j,D+e] + bcq[j]) * Wca[j] ----------------
__global__ __launch_bounds__(256) void k_pp2(const float* P, const void* Wcq, const void* bcq,
                                             const void* Wca, float* pp2, const int* flag){
  const int isbf = *flag;
  int bk = blockIdx.x;
  int t = bk >> 7, jt = bk & 127;
  int tid = threadIdx.x;
  int b = tid & 127;
  int ih = __builtin_amdgcn_readfirstlane(tid >> 7);
  int j0 = jt*4 + ih*2;
  float acc[2];
  #pragma unroll
  for (int kk = 0; kk < 2; kk++) acc[kk] = LDX(bcq, j0 + kk, isbf);
  if (isbf){
    const u16* w = (const u16*)Wcq;
    for (int e = 0; e < D; e += 8){
      float a[8];
      #pragma unroll
      for (int u = 0; u < 8; u++) a[u] = P[(size_t)(t*D + e + u)*BB + b];
      #pragma unroll
      for (int kk = 0; kk < 2; kk++){
        ushort4 w0 = *(const ushort4*)(w + (size_t)(j0+kk)*D2 + D + e);
        ushort4 w1 = *(const ushort4*)(w + (size_t)(j0+kk)*D2 + D + e + 4);
        acc[kk] += a[0]*bf2f(w0.x) + a[1]*bf2f(w0.y) + a[2]*bf2f(w0.z) + a[3]*bf2f(w0.w)
                 + a[4]*bf2f(w1.x) + a[5]*bf2f(w1.y) + a[6]*bf2f(w1.z) + a[7]*bf2f(w1.w);
      }
    }
  } else {
    const float* w = (const float*)Wcq;
    for (int e = 0; e < D; e += 8){
      float a[8];
      #pragma unroll
      for (int u = 0; u < 8; u++) a[u] = P[(size_t)(t*D + e + u)*BB + b];
      #pragma unroll
      for (int kk = 0; kk < 2; kk++){
        float4 w0 = *(const float4*)(w + (size_t)(j0+kk)*D2 + D + e);
        float4 w1 = *(const float4*)(w + (size_t)(j0+kk)*D2 + D + e + 4);
        acc[kk] += a[0]*w0.x + a[1]*w0.y + a[2]*w0.z + a[3]*w0.w
                 + a[4]*w1.x + a[5]*w1.y + a[6]*w1.z + a[7]*w1.w;
      }
    }
  }
  #pragma unroll
  for (int kk = 0; kk < 2; kk++)
    pp2[(size_t)(t*D + j0 + kk)*BB + b] = acc[kk] * LDX(Wca, j0 + kk, isbf);
}

// ---------------- K_initA: b-independent base vectors via K-split reduction ----------------
__global__ __launch_bounds__(256) void k_initA(const void* ctrl0, const void* mem0,
                                               const void* Wcq, const void* Wca,
                                               const void* Wrm, const void* brm,
                                               float* ubase, float* mmb, const int* flag){
  const int isbf = *flag;
  int bk = blockIdx.x, tid = threadIdx.x;
  int lane = tid & 63, w = tid >> 6;
  int grp = lane >> 3, k = lane & 7;
  int isU = (bk < 16);
  int o = (isU ? bk : bk - 16)*32 + w*8 + grp;
  const void* vec = isU ? ctrl0 : mem0;
  const void* mat = isU ? Wcq : Wrm;
  int ld = isU ? D2 : D;
  float acc = 0.f;
  #pragma unroll 4
  for (int it = 0; it < 16; it++){
    int d = it*32 + k*4;
    float4 v = LD4(vec, d, isbf);
    float4 m = LD4(mat, (size_t)o*ld + d, isbf);
    acc += v.x*m.x + v.y*m.y + v.z*m.z + v.w*m.w;
  }
  acc += __shfl_xor(acc, 1, 64);
  acc += __shfl_xor(acc, 2, 64);
  acc += __shfl_xor(acc, 4, 64);
  if (k == 0){
    if (isU) ubase[o] = acc * LDX(Wca, o, isbf);
    else     mmb[o]   = acc + LDX(brm, o, isbf);
  }
}

// ---------------- K_initB: broadcast u0, mm0, m_{-1}, zero wbuf ----------------
__global__ __launch_bounds__(256) void k_initB(const float* ubase, const float* mmb,
                                               const void* mem0, const float* pp2,
                                               float* u0, float* mm0, float* act0, float* wbuf,
                                               const int* flag){
  const int isbf = *flag;
  for (int idx = blockIdx.x*256 + threadIdx.x; idx < 3*D*BB + D2*BB; idx += 160*256){
    if (idx < D*BB)            u0[idx] = ubase[idx >> 7] + pp2[idx];
    else if (idx < 2*D*BB)   { int x = idx - D*BB;   mm0[x] = mmb[x >> 7]; }
    else if (idx < 3*D*BB)   { int x = idx - 2*D*BB; act0[D*BB + x] = LDX(mem0, x >> 7, isbf); }
    else                       wbuf[idx - 3*D*BB] = 0.f;
  }
}

// ---------------- K_A1: ctx attention (128 blocks) + mm gemv (64 blocks, t>=1) ----------------
// mm_t[i,b] += sum_d Wrm[i,d]*m_{t-1}[d,b]   (m_{t-1} = act_cur rows D..2D)
__global__ __launch_bounds__(512) void k_A1(const void* ctx, const float* ubuf, float* cbuf,
                                            const float* act_cur, float* mm_cur,
                                            const float* WrmTf, int t, const int* flag){
  int bk = blockIdx.x, tid = threadIdx.x;
  if (bk >= BB){
    if (t == 0) return;
    int l = bk - BB;                       // 0..63
    int b = tid & 127;
    int ih = (tid >> 7) & 3;               // 4 groups
    int it = l >> 2, kc = l & 3;
    int i0 = it*32 + ih*8;
    float acc[8] = {0.f,0.f,0.f,0.f,0.f,0.f,0.f,0.f};
    int d0 = kc*128;
    for (int d = d0; d < d0 + 128; d += 8){
      float av[8];
      #pragma unroll
      for (int u = 0; u < 8; u++) av[u] = act_cur[(size_t)(D + d + u)*BB + b];
      #pragma unroll
      for (int u = 0; u < 8; u++){
        float4 w0 = *(const float4*)(WrmTf + (size_t)(d+u)*D + i0);
        float4 w1 = *(const float4*)(WrmTf + (size_t)(d+u)*D + i0 + 4);
        acc[0]+=av[u]*w0.x; acc[1]+=av[u]*w0.y; acc[2]+=av[u]*w0.z; acc[3]+=av[u]*w0.w;
        acc[4]+=av[u]*w1.x; acc[5]+=av[u]*w1.y; acc[6]+=av[u]*w1.z; acc[7]+=av[u]*w1.w;
      }
    }
    #pragma unroll
    for (int kk = 0; kk < 8; kk++) atomicAdd(&mm_cur[(size_t)(i0 + kk)*BB + b], acc[kk]);
    return;
  }
  const int isbf = *flag;
  __shared__ float lg[SS];
  __shared__ float red[128];
  int b = bk;
  int lane = tid & 63, wv = tid >> 6;         // 8 waves
  float ur[8];
  #pragma unroll
  for (int kk = 0; kk < 8; kk++) ur[kk] = ubuf[(lane*8 + kk)*BB + b];
  for (int s = wv; s < SS; s += 16){
    int s2 = s + 8;
    float dotA, dotB;
    if (isbf){
      const u16* crowA = (const u16*)ctx + ((size_t)(b*SS + s ))*D + lane*8;
      const u16* crowB = (const u16*)ctx + ((size_t)(b*SS + s2))*D + lane*8;
      ushort4 a0 = *(const ushort4*)crowA, a1 = *(const ushort4*)(crowA + 4);
      ushort4 b0 = *(const ushort4*)crowB, b1 = *(const ushort4*)(crowB + 4);
      dotA = ur[0]*bf2f(a0.x) + ur[1]*bf2f(a0.y) + ur[2]*bf2f(a0.z) + ur[3]*bf2f(a0.w)
           + ur[4]*bf2f(a1.x) + ur[5]*bf2f(a1.y) + ur[6]*bf2f(a1.z) + ur[7]*bf2f(a1.w);
      dotB = ur[0]*bf2f(b0.x) + ur[1]*bf2f(b0.y) + ur[2]*bf2f(b0.z) + ur[3]*bf2f(b0.w)
           + ur[4]*bf2f(b1.x) + ur[5]*bf2f(b1.y) + ur[6]*bf2f(b1.z) + ur[7]*bf2f(b1.w);
    } else {
      const float* crowA = (const float*)ctx + ((size_t)(b*SS + s ))*D + lane*8;
      const float* crowB = (const float*)ctx + ((size_t)(b*SS + s2))*D + lane*8;
      float4 a0 = *(const float4*)crowA, a1 = *(const float4*)(crowA + 4);
      float4 b0 = *(const float4*)crowB, b1 = *(const float4*)(crowB + 4);
      dotA = ur[0]*a0.x + ur[1]*a0.y + ur[2]*a0.z + ur[3]*a0.w
           + ur[4]*a1.x + ur[5]*a1.y + ur[6]*a1.z + ur[7]*a1.w;
      dotB = ur[0]*b0.x + ur[1]*b0.y + ur[2]*b0.z + ur[3]*b0.w
           + ur[4]*b1.x + ur[5]*b1.y + ur[6]*b1.z + ur[7]*b1.w;
    }
    #pragma unroll
    for (int off = 32; off; off >>= 1){
      dotA += __shfl_down(dotA, off, 64);
      dotB += __shfl_down(dotB, off, 64);
    }
    if (lane == 0){ lg[s] = dotA; lg[s2] = dotB; }
  }
  __syncthreads();
  if (tid < 128) red[tid] = lg[tid];
  __syncthreads();
  for (int off = 64; off; off >>= 1){ if (tid < off) red[tid] = fmaxf(red[tid], red[tid+off]); __syncthreads(); }
  float M = red[0];
  __syncthreads();
  if (tid < 128){ float e = __expf(lg[tid] - M); lg[tid] = e; red[tid] = e; }
  __syncthreads();
  for (int off = 64; off; off >>= 1){ if (tid < off) red[tid] += red[tid+off]; __syncthreads(); }
  float inv = 1.f / red[0];
  int d = tid;
  float a[8];
  #pragma unroll
  for (int u = 0; u < 8; u++) a[u] = 0.f;
  if (isbf){
    const u16* cb = (const u16*)ctx + ((size_t)b*SS)*D + d;
    for (int s = 0; s < SS; s += 8){
      #pragma unroll
      for (int u = 0; u < 8; u++) a[u] += lg[s+u]*bf2f(cb[(size_t)(s+u)*D]);
    }
  } else {
    const float* cb = (const float*)ctx + ((size_t)b*SS)*D + d;
    for (int s = 0; s < SS; s += 8){
      #pragma unroll
      for (int u = 0; u < 8; u++) a[u] += lg[s+u]*cb[(size_t)(s+u)*D];
    }
  }
  cbuf[d*BB + b] = (((a[0]+a[1]) + (a[2]+a[3])) + ((a[4]+a[5]) + (a[6]+a[7]))) * inv;
}

// ---------------- K_G2: w += c@W2f (atomic, K-split x4) + preload next-step accumulators ----------------
__global__ __launch_bounds__(256) void k_G2(const float* cbuf, const float* W2f, float* wbuf,
                                            const float* pp2_next, float* u_nxt,
                                            const void* brm, float* mm_nxt,
                                            const void* bwc, float* act_nxt, int t, const int* flag){
  int bk = blockIdx.x, tid = threadIdx.x;
  if (bk < 512){
    int et = bk >> 2, kc = bk & 3;
    int b = tid & 127;
    int ih = __builtin_amdgcn_readfirstlane(tid >> 7);
    int e0 = et*8 + ih*4;
    float acc[4] = {0.f, 0.f, 0.f, 0.f};
    int j0 = kc*128;
    for (int j = j0; j < j0 + 128; j += 8){
      float av[8];
      #pragma unroll
      for (int u = 0; u < 8; u++) av[u] = cbuf[(j+u)*BB + b];
      #pragma unroll
      for (int u = 0; u < 8; u++){
        float4 wv = *(const float4*)(W2f + (size_t)(j+u)*D2 + e0);
        acc[0] += av[u]*wv.x; acc[1] += av[u]*wv.y;
        acc[2] += av[u]*wv.z; acc[3] += av[u]*wv.w;
      }
    }
    #pragma unroll
    for (int kk = 0; kk < 4; kk++) atomicAdd(&wbuf[(e0+kk)*BB + b], acc[kk]);
  } else if (bk < 528){
    if (t < TT-1)
      for (int x = (bk-512)*256 + tid; x < D*BB; x += 16*256) u_nxt[x] = pp2_next[x];
  } else if (bk < 544){
    if (t < TT-1){
      const int isbf = *flag;
      for (int x = (bk-528)*256 + tid; x < D*BB; x += 16*256)
        mm_nxt[x] = LDX(brm, x >> 7, isbf);
    }
  } else {
    const int isbf = *flag;
    if (isbf){
      const u16* w = (const u16*)bwc;
      for (int x = (bk-544)*256 + tid; x < D*BB; x += 16*256) act_nxt[D*BB + x] = bf2f(w[x >> 7]);
    } else {
      const float* w = (const float*)bwc;
      for (int x = (bk-544)*256 + tid; x < D*BB; x += 16*256) act_nxt[D*BB + x] = w[x >> 7];
    }
  }
}

// ---------------- K_A2: k attention (per-batch block, 512 thr) -> r into act_cur ----------------
__global__ __launch_bounds__(512) void k_A2(const void* kmat, const float* wbuf,
                                            const float* mmbuf, float* act_cur, const int* flag){
  const int isbf = *flag;
  int b = blockIdx.x, tid = threadIdx.x;
  __shared__ float u2[D];
  __shared__ float lg[256];
  __shared__ float red[256];
  __shared__ float ps[2][256];
  u2[tid] = wbuf[tid*BB + b]*mmbuf[tid*BB + b] + wbuf[(D + tid)*BB + b];
  __syncthreads();
  {
    int half = tid >> 8;
    int n = tid & 255;
    float part = 0.f;
    if (n < NN){
      float c[8];
      #pragma unroll
      for (int u = 0; u < 8; u++) c[u] = 0.f;
      int d0 = half*256;
      if (isbf){
        const u16* kb = (const u16*)kmat + (size_t)b*D*NN + n;
        for (int dd = 0; dd < 256; dd += 8){
          #pragma unroll
          for (int u = 0; u < 8; u++) c[u] += u2[d0+dd+u]*bf2f(kb[(size_t)(d0+dd+u)*NN]);
        }
      } else {
        const float* kb = (const float*)kmat + (size_t)b*D*NN + n;
        for (int dd = 0; dd < 256; dd += 8){
          #pragma unroll
          for (int u = 0; u < 8; u++) c[u] += u2[d0+dd+u]*kb[(size_t)(d0+dd+u)*NN];
        }
      }
      part = (((c[0]+c[1]) + (c[2]+c[3])) + ((c[4]+c[5]) + (c[6]+c[7])));
    }
    ps[half][n] = part;
  }
  __syncthreads();
  if (tid < 256){
    float logit = (tid < NN) ? (ps[0][tid] + ps[1][tid]) : -INFINITY;
    lg[tid] = logit; red[tid] = logit;
  }
  __syncthreads();
  for (int off = 128; off; off >>= 1){ if (tid < off) red[tid] = fmaxf(red[tid], red[tid+off]); __syncthreads(); }
  float M = red[0];
  __syncthreads();
  if (tid < 256){ float e = (tid < NN) ? __expf(lg[tid] - M) : 0.f; lg[tid] = e; red[tid] = e; }
  __syncthreads();
  for (int off = 128; off; off >>= 1){ if (tid < off) red[tid] += red[tid+off]; __syncthreads(); }
  float inv = 1.f / red[0];
  int lane = tid & 63, wv = tid >> 6;
  for (int i = 0; i < 32; i++){
    int dA = wv + i*16, dB = dA + 8;
    float p, qv;
    if (isbf){
      const u16* krA = (const u16*)kmat + (size_t)b*D*NN + (size_t)dA*NN;
      const u16* krB = (const u16*)kmat + (size_t)b*D*NN + (size_t)dB*NN;
      p  = lg[lane]*bf2f(krA[lane]) + lg[lane+64]*bf2f(krA[lane+64]) + lg[lane+128]*bf2f(krA[lane+128]);
      qv = lg[lane]*bf2f(krB[lane]) + lg[lane+64]*bf2f(krB[lane+64]) + lg[lane+128]*bf2f(krB[lane+128]);
      if (lane < NN - 192){
        p  += lg[lane+192]*bf2f(krA[lane+192]);
        qv += lg[lane+192]*bf2f(krB[lane+192]);
      }
    } else {
      const float* krA = (const float*)kmat + (size_t)b*D*NN + (size_t)dA*NN;
      const float* krB = (const float*)kmat + (size_t)b*D*NN + (size_t)dB*NN;
      p  = lg[lane]*krA[lane] + lg[lane+64]*krA[lane+64] + lg[lane+128]*krA[lane+128];
      qv = lg[lane]*krB[lane] + lg[lane+64]*krB[lane+64] + lg[lane+128]*krB[lane+128];
      if (lane < NN - 192){
        p  += lg[lane+192]*krA[lane+192];
        qv += lg[lane+192]*krB[lane+192];
      }
    }
    #pragma unroll
    for (int off = 32; off; off >>= 1){
      p  += __shfl_down(p , off, 64);
      qv += __shfl_down(qv, off, 64);
    }
    if (lane == 0){
      act_cur[dA*BB + b] = p  * inv;
      act_cur[dB*BB + b] = qv * inv;
    }
  }
}

// ---------------- K_G3: m, u_next (atomic K-split gemvs) + zero wbuf for next step ----------------
__global__ __launch_bounds__(256) void k_G3(const float* act_cur, const float* cbuf,
                                            const float* Wwcf, const float* W1f,
                                            float* act_nxt, float* u_nxt, float* wbuf,
                                            int t){
  int bk = blockIdx.x, tid = threadIdx.x;
  int b = tid & 127;
  int ih = __builtin_amdgcn_readfirstlane(tid >> 7);
  if (bk < 256){
    int it = bk >> 3, kc = bk & 7;
    int i0 = it*16 + ih*8;
    float acc[8] = {0.f,0.f,0.f,0.f,0.f,0.f,0.f,0.f};
    int e0 = kc*128;
    for (int e = e0; e < e0 + 128; e += 8){
      float av[8];
      #pragma unroll
      for (int u = 0; u < 8; u++) av[u] = act_cur[(e+u)*BB + b];
      #pragma unroll
      for (int u = 0; u < 8; u++){
        float4 w0 = *(const float4*)(Wwcf + (size_t)(e+u)*D + i0);
        float4 w1 = *(const float4*)(Wwcf + (size_t)(e+u)*D + i0 + 4);
        acc[0]+=av[u]*w0.x; acc[1]+=av[u]*w0.y; acc[2]+=av[u]*w0.z; acc[3]+=av[u]*w0.w;
        acc[4]+=av[u]*w1.x; acc[5]+=av[u]*w1.y; acc[6]+=av[u]*w1.z; acc[7]+=av[u]*w1.w;
      }
    }
    #pragma unroll
    for (int kk = 0; kk < 8; kk++) atomicAdd(&act_nxt[(size_t)(D + i0 + kk)*BB + b], acc[kk]);
  } else if (bk < 384){
    if (t == TT-1) return;
    int l = bk - 256;
    int it = l >> 2, kc = l & 3;
    int j0 = it*16 + ih*8;
    float acc[8] = {0.f,0.f,0.f,0.f,0.f,0.f,0.f,0.f};
    int e0 = kc*128;
    for (int e = e0; e < e0 + 128; e += 8){
      float av[8];
      #pragma unroll
      for (int u = 0; u < 8; u++) av[u] = cbuf[(e+u)*BB + b];
      #pragma unroll
      for (int u = 0; u < 8; u++){
        float4 w0 = *(const float4*)(W1f + (size_t)(e+u)*D + j0);
        float4 w1 = *(const float4*)(W1f + (size_t)(e+u)*D + j0 + 4);
        acc[0]+=av[u]*w0.x; acc[1]+=av[u]*w0.y; acc[2]+=av[u]*w0.z; acc[3]+=av[u]*w0.w;
        acc[4]+=av[u]*w1.x; acc[5]+=av[u]*w1.y; acc[6]+=av[u]*w1.z; acc[7]+=av[u]*w1.w;
      }
    }
    #pragma unroll
    for (int kk = 0; kk < 8; kk++) atomicAdd(&u_nxt[(j0 + kk)*BB + b], acc[kk]);
  } else {
    if (t == TT-1) return;
    for (int x = (bk-384)*256 + tid; x < D2*BB; x += 16*256) wbuf[x] = 0.f;
  }
}

// ---------------- K_out: m[i,b] fp32 -> out[b,i] (bf16 or f32) ----------------
__global__ __launch_bounds__(256) void k_out(const float* act_fin, void* out, const int* flag){
  const int isbf = *flag;
  __shared__ float lds[32][33];
  int bk = blockIdx.x;
  int it = bk >> 2, bt = bk & 3;
  int tx = threadIdx.x & 31, ty = threadIdx.x >> 5;
  #pragma unroll
  for (int kk = 0; kk < 4; kk++){
    int i = it*32 + ty + kk*8;
    lds[tx][ty + kk*8] = act_fin[(D + i)*BB + bt*32 + tx];
  }
  __syncthreads();
  if (isbf){
    __hip_bfloat16* o = (__hip_bfloat16*)out;
    #pragma unroll
    for (int kk = 0; kk < 4; kk++){
      int bb = bt*32 + ty + kk*8;
      o[(size_t)bb*D + it*32 + tx] = __float2bfloat16(lds[ty + kk*8][tx]);
    }
  } else {
    float* o = (float*)out;
    #pragma unroll
    for (int kk = 0; kk < 4; kk++){
      int bb = bt*32 + ty + kk*8;
      o[(size_t)bb*D + it*32 + tx] = lds[ty + kk*8][tx];
    }
  }
}

extern "C" void kernel_launch(void* const* d_in, const int* in_sizes, int n_in,
                              void* d_out, int out_size, void* d_ws, size_t ws_size,
                              hipStream_t stream){
  const void* ctx  = d_in[0];
  const void* q    = d_in[1];
  const void* kmat = d_in[2];
  const void* mem0 = d_in[3];
  const void* ctrl0= d_in[4];
  const void* Wp   = d_in[5];
  const void* bp   = d_in[6];
  const void* Wcq  = d_in[7];
  const void* bcq  = d_in[8];
  const void* Wca  = d_in[9];
  const void* Wrm  = d_in[11];
  const void* brm  = d_in[12];
  const void* Wrc  = d_in[13];
  const void* Wra  = d_in[15];
  const void* Wwc  = d_in[17];
  const void* bwc  = d_in[18];

  float* W      = (float*)d_ws;
  float* qT     = W;
  float* P      = W + 131072;
  float* pp2    = W + 917504;
  float* W1f    = W + 1703936;
  float* W2f    = W + 1966080;
  float* Wwcf   = W + 2490368;
  float* WrmTf  = W + 3014656;
  float* ubuf   = W + 3801600;   // 2 x 65536
  float* cbuf   = W + 3932672;
  float* wbuf   = W + 3998208;
  float* mmbuf  = W + 4129280;   // 2 x 65536
  float* actb   = W + 4260352;   // 2 x 131072
  int*   flag   = (int*)(W + 4522496);
  float* ubase  = W + 4522560;   // 512
  float* mmb    = W + 4523072;   // 512

  hipLaunchKernelGGL(k_detect, dim3(1), dim3(256), 0, stream, (const u16*)ctx, flag);
  hipLaunchKernelGGL(k_prep1, dim3(1216), dim3(256), 0, stream,
                     q, Wcq, Wca, Wwc, Wrm, Wrc, Wra, qT, W1f, Wwcf, WrmTf, W2f, flag);
  hipLaunchKernelGGL(k_P,    dim3(1536), dim3(256), 0, stream, qT, Wp, bp, P, flag);
  hipLaunchKernelGGL(k_pp2,  dim3(1536), dim3(256), 0, stream, P, Wcq, bcq, Wca, pp2, flag);
  hipLaunchKernelGGL(k_initA, dim3(32), dim3(256), 0, stream,
                     ctrl0, mem0, Wcq, Wca, Wrm, brm, ubase, mmb, flag);
  hipLaunchKernelGGL(k_initB, dim3(160), dim3(256), 0, stream,
                     ubase, mmb, mem0, pp2, ubuf, mmbuf, actb, wbuf, flag);

  for (int t = 0; t < TT; t++){
    int cur = t & 1, nxt = 1 - cur;
    hipLaunchKernelGGL(k_A1, dim3(192), dim3(512), 0, stream,
                       ctx, ubuf + cur*65536, cbuf,
                       actb + cur*131072, mmbuf + cur*65536, WrmTf, t, flag);
    hipLaunchKernelGGL(k_G2, dim3(560), dim3(256), 0, stream,
                       cbuf, W2f, wbuf,
                       pp2 + ((t+1 < TT) ? (t+1)*65536 : 0), ubuf + nxt*65536,
                       brm, mmbuf + nxt*65536,
                       bwc, actb + nxt*131072, t, flag);
    hipLaunchKernelGGL(k_A2, dim3(128), dim3(512), 0, stream,
                       kmat, wbuf, mmbuf + cur*65536, actb + cur*131072, flag);
    hipLaunchKernelGGL(k_G3, dim3(400), dim3(256), 0, stream,
                       actb + cur*131072, cbuf, Wwcf, W1f,
                       actb + nxt*131072, ubuf + nxt*65536, wbuf, t);
  }
  hipLaunchKernelGGL(k_out, dim3(64), dim3(256), 0, stream, actb, d_out, flag);
}